// Round 11
// baseline (3718.999 us; speedup 1.0000x reference)
//
#include <hip/hip_runtime.h>
#include <math.h>

#define B_ 256
#define N_ 127
#define S_ 128
#define NDIM_ 3
#define D_ 256
#define H_ 8
#define DH_ 32
#define M_ 256
#define HID_ 256
#define L_ 4
#define LOG2E 1.44269504088896340736f

typedef __attribute__((ext_vector_type(8))) short short8;
typedef __attribute__((ext_vector_type(4))) float floatx4;

// ---------- bf16 split helpers ----------
__device__ __forceinline__ ushort bf16_rn(float x) {
    unsigned u = __float_as_uint(x);
    u = (u + 0x7fffu + ((u >> 16) & 1u)) >> 16;
    return (ushort)u;
}
__device__ __forceinline__ void split2(float x, unsigned& hh, unsigned& ll) {
    const ushort h = bf16_rn(x);
    const float r = x - __uint_as_float(((unsigned)h) << 16);
    const ushort l = bf16_rn(r);
    hh = (unsigned)h * 0x10001u;
    ll = (unsigned)l * 0x10001u;
}
__device__ __forceinline__ unsigned split_pack(float x) {
    const ushort h = bf16_rn(x);
    const float r = x - __uint_as_float(((unsigned)h) << 16);
    const ushort l = bf16_rn(r);
    return (unsigned)h | ((unsigned)l << 16);
}

// ---------- block reductions ----------
__device__ __forceinline__ float blk_sum(float v, float* sred) {
#pragma unroll
    for (int o = 32; o > 0; o >>= 1) v += __shfl_xor(v, o, 64);
    if ((threadIdx.x & 63) == 0) sred[threadIdx.x >> 6] = v;
    __syncthreads();
    v = sred[0] + sred[1] + sred[2] + sred[3];
    __syncthreads();
    return v;
}

// ---------- embedding ----------
__global__ void k_embed(const float* __restrict__ x, const float* __restrict__ ew,
                        const float* __restrict__ eb, float* __restrict__ h) {
    const int idx = blockIdx.x * 256 + threadIdx.x;
    const int d = idx & (D_ - 1);
    const int n = (idx >> 8) & (S_ - 1);
    const int b = idx >> 15;
    float val = 0.f;
    if (n > 0) {
        const float* xr = x + ((size_t)b * N_ + (n - 1)) * NDIM_;
        val = eb[d] + xr[0] * ew[d * 3 + 0] + xr[1] * ew[d * 3 + 1] + xr[2] * ew[d * 3 + 2];
    }
    h[idx] = val;
}

// ---------- proj pre-split (compact): fp32 -> uint [h|l<<16] (k_dmax/k_attn2 format) ----------
__global__ void __launch_bounds__(256) k_wconv(const float* __restrict__ src, unsigned* __restrict__ dst) {
    const int idx = (blockIdx.x * 256 + threadIdx.x) * 4;
    const float4 w4 = *(const float4*)&src[idx];
    const float v[4] = {w4.x, w4.y, w4.z, w4.w};
    unsigned u[4];
#pragma unroll
    for (int i = 0; i < 4; i++) u[i] = split_pack(v[i]);
    *(uint4*)&dst[idx] = make_uint4(u[0], u[1], u[2], u[3]);
}

// ---------- weight pre-expand: B-fragment-native layout ----------
// Per layer-matrix (256 cols x 256 k): WT uint index ((s*256+col)*4+q)*4 holds
// {hh(o0), ll(o0), hh(o1), ll(o1)}, o0 = s*8+2q, o1 = o0+1  (B-pattern {h,h,l,l}).
// One matrix = 131072 uints (512 KB). Grid: L*256*128/256 = 512 blocks per tensor.
__global__ void __launch_bounds__(256) k_wconvx(const float* __restrict__ src, unsigned* __restrict__ dst) {
    const int idx = blockIdx.x * 256 + threadIdx.x;   // over L*256*128 orig-pairs
    const int l = idx >> 15;
    const int rem = idx & 32767;
    const int col = rem >> 7, op = rem & 127;         // op = orig pair 0..127
    const float2 v = *(const float2*)&src[((size_t)(l * 256 + col)) * 256 + op * 2];
    unsigned hh0, ll0, hh1, ll1;
    split2(v.x, hh0, ll0);
    split2(v.y, hh1, ll1);
    const int s = op >> 2, q = op & 3;
    unsigned* d = dst + (size_t)l * 131072 + ((size_t)(s * 256 + col) * 4 + q) * 4;
    *(uint4*)d = make_uint4(hh0, ll0, hh1, ll1);
}

// ---------- MFMA bf16x2-split GEMM v2: C[64 x 256], W streamed from global ----------
// A-pattern {h,l,h,l} (packed uint dup, staged in LDS per 32-orig chunk);
// B-pattern {h,h,l,l} (pre-expanded WT, coalesced dwordx4 per col-tile, NO LDS).
// 16 barriers/block (vs 64). EPI: 0 q/k layout; 1 +mask (v); 2 LayerNorm; 3 leaky.
template<int EPI>
__global__ void __launch_bounds__(256, 4) k_gemm(
    const float* __restrict__ A, const unsigned* __restrict__ WT,
    const float* __restrict__ bias, const float* __restrict__ g1,
    const float* __restrict__ g2, const int* __restrict__ mask,
    float* __restrict__ out)
{
    __shared__ ushort A2s[64 * 136];       // [row][32 origs -> 128 k2, stride 136]
    __shared__ float sredA[64][2], sredB[64][2];
    const int t = threadIdx.x;
    const int w = t >> 6, lane = t & 63;
    const int quad = lane >> 4, l16 = lane & 15;
    const int rowbase = 32 * (w >> 1), colbase = 128 * (w & 1);
    const int row0 = blockIdx.x * 64;

    floatx4 acc[2][8];
#pragma unroll
    for (int rt = 0; rt < 2; rt++)
#pragma unroll
        for (int ct = 0; ct < 8; ct++) acc[rt][ct] = (floatx4){0.f, 0.f, 0.f, 0.f};

    const int srow = t >> 2, sg = t & 3;   // staging: row, 8-orig group
    const float* Arow = A + (size_t)(row0 + srow) * D_ + sg * 8;

    for (int ch = 0; ch < 8; ch++) {       // 8 chunks x 32 origs
        __syncthreads();
        {   // stage A chunk: this thread 8 origs -> 4 uint4 {p,p,p',p'}
            float vv[8];
            *(float4*)&vv[0] = *(const float4*)&Arow[ch * 32];
            *(float4*)&vv[4] = *(const float4*)&Arow[ch * 32 + 4];
#pragma unroll
            for (int p = 0; p < 4; p++) {
                const unsigned p0 = split_pack(vv[2 * p]);
                const unsigned p1 = split_pack(vv[2 * p + 1]);
                *(uint4*)&A2s[srow * 136 + sg * 32 + p * 8] = make_uint4(p0, p0, p1, p1);
            }
        }
        __syncthreads();
#pragma unroll
        for (int ss = 0; ss < 4; ss++) {
            const int s = ch * 4 + ss;
            short8 af[2], bf[8];
#pragma unroll
            for (int rt = 0; rt < 2; rt++)
                af[rt] = *(const short8*)&A2s[(rowbase + 16 * rt + l16) * 136 + ss * 32 + quad * 8];
#pragma unroll
            for (int ct = 0; ct < 8; ct++)
                bf[ct] = *(const short8*)&WT[((size_t)(s * 256 + colbase + 16 * ct + l16) * 4 + quad) * 4];
#pragma unroll
            for (int rt = 0; rt < 2; rt++)
#pragma unroll
                for (int ct = 0; ct < 8; ct++)
                    acc[rt][ct] = __builtin_amdgcn_mfma_f32_16x16x32_bf16(af[rt], bf[ct], acc[rt][ct], 0, 0, 0);
        }
    }

    int colv[8]; float bv[8];
#pragma unroll
    for (int ct = 0; ct < 8; ct++) { colv[ct] = colbase + 16 * ct + l16; bv[ct] = bias[colv[ct]]; }

    if (EPI <= 1) {
        const int b = row0 >> 7;
#pragma unroll
        for (int rt = 0; rt < 2; rt++)
#pragma unroll
        for (int i = 0; i < 4; i++) {
            const int rl = rowbase + 16 * rt + quad * 4 + i;
            const int n = (row0 + rl) & (S_ - 1);
            float keep = 1.f;
            if (EPI == 1) keep = (n == 0) ? 1.f : (mask[b * N_ + n - 1] ? 0.f : 1.f);
#pragma unroll
            for (int ct = 0; ct < 8; ct++) {
                float c = acc[rt][ct][i] + bv[ct];
                if (EPI == 1) c *= keep;
                const int col = colv[ct];
                out[(((size_t)b * H_ + (col >> 5)) * S_ + n) * DH_ + (col & 31)] = c;
            }
        }
    } else if (EPI == 2) {
        float gv[8], bbv[8];
#pragma unroll
        for (int ct = 0; ct < 8; ct++) { gv[ct] = g1[colv[ct]]; bbv[ct] = g2[colv[ct]]; }
#pragma unroll
        for (int rt = 0; rt < 2; rt++)
#pragma unroll
        for (int i = 0; i < 4; i++) {
            const int rl = rowbase + 16 * rt + quad * 4 + i;
            float s = 0.f, s2 = 0.f;
#pragma unroll
            for (int ct = 0; ct < 8; ct++) {
                const float c = acc[rt][ct][i] + bv[ct];
                s += c; s2 += c * c;
            }
#pragma unroll
            for (int o = 8; o > 0; o >>= 1) { s += __shfl_xor(s, o, 64); s2 += __shfl_xor(s2, o, 64); }
            if (l16 == 0) { sredA[rl][w & 1] = s; sredB[rl][w & 1] = s2; }
        }
        __syncthreads();
#pragma unroll
        for (int rt = 0; rt < 2; rt++)
#pragma unroll
        for (int i = 0; i < 4; i++) {
            const int rl = rowbase + 16 * rt + quad * 4 + i;
            const float s = sredA[rl][0] + sredA[rl][1];
            const float s2 = sredB[rl][0] + sredB[rl][1];
            const float mu = s * (1.f / D_);
            const float rs = rsqrtf(s2 * (1.f / D_) - mu * mu + 1e-5f);
#pragma unroll
            for (int ct = 0; ct < 8; ct++) {
                const float c = acc[rt][ct][i] + bv[ct];
                out[(size_t)(row0 + rl) * D_ + colv[ct]] = (c - mu) * rs * gv[ct] + bbv[ct];
            }
        }
    } else {
#pragma unroll
        for (int rt = 0; rt < 2; rt++)
#pragma unroll
        for (int i = 0; i < 4; i++) {
            const int rl = rowbase + 16 * rt + quad * 4 + i;
#pragma unroll
            for (int ct = 0; ct < 8; ct++) {
                const float c = acc[rt][ct][i] + bv[ct];
                out[(size_t)(row0 + rl) * D_ + colv[ct]] = (c >= 0.f) ? c : 0.2f * c;
            }
        }
    }
}

// ---------- reset kmax slots ----------
__global__ void k_reset(int* slots) {
    if (threadIdx.x < 4) {
        const int i = __float_as_int(-INFINITY);
        slots[threadIdx.x] = (i >= 0) ? i : (i ^ 0x7fffffff);
    }
}

// ---------- MFMA global k-max (proven, compact P2 format) ----------
__global__ void __launch_bounds__(256) k_dmax(
    const float* __restrict__ kg, const unsigned* __restrict__ P2, int* __restrict__ slot)
{
    __shared__ __align__(16) ushort A2s[64 * 136];
    __shared__ __align__(16) ushort Ps[128 * 136];
    __shared__ float sred[4];
    const int t = threadIdx.x;
    const size_t row0 = (size_t)(blockIdx.x >> 1) * 64;
    const int m0 = (blockIdx.x & 1) * 128;
    {
        const int row = t >> 2, kq = (t & 3) * 8;
        const float* src = kg + (row0 + row) * DH_ + kq;
        const float4 f0 = *(const float4*)src;
        const float4 f1 = *(const float4*)(src + 4);
        const float vv[8] = {f0.x, f0.y, f0.z, f0.w, f1.x, f1.y, f1.z, f1.w};
#pragma unroll
        for (int i = 0; i < 4; i++) {
            unsigned hh0, ll0, hh1, ll1;
            split2(vv[2 * i], hh0, ll0); split2(vv[2 * i + 1], hh1, ll1);
            *(uint4*)&A2s[row * 136 + ((t & 3) * 4 + i) * 8] = make_uint4(hh0, ll0, hh1, ll1);
        }
    }
    {
        const int col = t >> 1;
        const unsigned* src = P2 + (m0 + col) * DH_ + (t & 1) * 16;
#pragma unroll
        for (int i = 0; i < 8; i++) {
            const unsigned u0 = src[2 * i], u1 = src[2 * i + 1];
            *(uint4*)&Ps[col * 136 + ((t & 1) * 8 + i) * 8] = make_uint4(u0, u0, u1, u1);
        }
    }
    __syncthreads();
    const int w = t >> 6, lane = t & 63, quad = lane >> 4, l16 = lane & 15;
    floatx4 acc[4][2];
#pragma unroll
    for (int rt = 0; rt < 4; rt++)
#pragma unroll
        for (int ct = 0; ct < 2; ct++) acc[rt][ct] = (floatx4){0.f, 0.f, 0.f, 0.f};
#pragma unroll
    for (int kk = 0; kk < 4; kk++) {
        short8 af[4], bf[2];
#pragma unroll
        for (int rt = 0; rt < 4; rt++)
            af[rt] = *(const short8*)&A2s[(rt * 16 + l16) * 136 + (kk * 4 + quad) * 8];
#pragma unroll
        for (int ct = 0; ct < 2; ct++)
            bf[ct] = *(const short8*)&Ps[((w * 2 + ct) * 16 + l16) * 136 + (kk * 4 + quad) * 8];
#pragma unroll
        for (int rt = 0; rt < 4; rt++)
#pragma unroll
            for (int ct = 0; ct < 2; ct++)
                acc[rt][ct] = __builtin_amdgcn_mfma_f32_16x16x32_bf16(af[rt], bf[ct], acc[rt][ct], 0, 0, 0);
    }
    float mx = -INFINITY;
#pragma unroll
    for (int rt = 0; rt < 4; rt++)
#pragma unroll
        for (int ct = 0; ct < 2; ct++)
#pragma unroll
            for (int i = 0; i < 4; i++) mx = fmaxf(mx, acc[rt][ct][i]);
#pragma unroll
    for (int o = 32; o > 0; o >>= 1) mx = fmaxf(mx, __shfl_xor(mx, o, 64));
    if (lane == 0) sred[w] = mx;
    __syncthreads();
    if (t == 0) {
        const float m4 = fmaxf(fmaxf(sred[0], sred[1]), fmaxf(sred[2], sred[3]))
                       * 0.42044820762685725f;
        const int i = __float_as_int(m4);
        atomicMax(slot, (i >= 0) ? i : (i ^ 0x7fffffff));
    }
}

// ---------- full-MFMA performer attention, 1024 threads (16 waves), 140 KB LDS ----------
__global__ void __launch_bounds__(1024) k_attn2(
    const float* __restrict__ qg, const float* __restrict__ kg, const float* __restrict__ vg,
    const unsigned* __restrict__ P2, const int* __restrict__ slot,
    float* __restrict__ outp)
{
    extern __shared__ char smem[];
    ushort* sA    = (ushort*)(smem);            // [128][136]: K-split, then Q-split
    ushort* sB    = (ushort*)(smem + 34816);    // [64][136]: P-quarter {h,l,h,l}
    ushort* sBig  = (ushort*)(smem + 52224);    // kpT [64][264] / qpA [128][136]
    ushort* sV    = (ushort*)(smem + 87040);    // [32][264]: v dup
    ushort* sCtx  = (ushort*)(smem + 103936);   // [32][520]: ctx dup
    float* sdk    = (float*)(smem + 137216);    // [128]
    float* sdq    = (float*)(smem + 137728);    // [128]
    float* smaxP  = (float*)(smem + 138240);    // [2][128]
    float* sdenP  = (float*)(smem + 139264);    // [2][128]
    float* sksum  = (float*)(smem + 140288);    // [256]
    float* sksP   = (float*)(smem + 141312);    // [16][32]

    const int bh = blockIdx.x;
    const int b = bh >> 3, hh = bh & 7;
    const int t = threadIdx.x;
    const int w = t >> 6, lane = t & 63, quad = lane >> 4, l16 = lane & 15;
    const int wg = w & 7, wh = w >> 3;
    const float* kb = kg + (size_t)bh * S_ * DH_;
    const float* qb = qg + (size_t)bh * S_ * DH_;
    const float* vb = vg + (size_t)bh * S_ * DH_;
    const float nrm = 0.42044820762685725f;
    const float diagc = 0.5f * nrm * nrm;
    const float ratio = 0.0625f;

    if (t < 512) {
        const int row = t >> 2, seg = t & 3;
        const float* src = kb + row * DH_ + seg * 8;
        float vv[8];
        *(float4*)&vv[0] = *(const float4*)&src[0];
        *(float4*)&vv[4] = *(const float4*)&src[4];
#pragma unroll
        for (int p = 0; p < 4; p++) {
            unsigned hh0, ll0, hh1, ll1;
            split2(vv[2 * p], hh0, ll0); split2(vv[2 * p + 1], hh1, ll1);
            *(uint4*)&sA[row * 136 + seg * 32 + p * 8] = make_uint4(hh0, ll0, hh1, ll1);
        }
    } else {
        const int tt2 = t - 512;
        const int n = tt2 & 127, d0 = (tt2 >> 7) * 8;
        const float* src = vb + n * DH_ + d0;
        float vv[8];
        *(float4*)&vv[0] = *(const float4*)&src[0];
        *(float4*)&vv[4] = *(const float4*)&src[4];
        unsigned* dst = (unsigned*)sV;
#pragma unroll
        for (int j = 0; j < 8; j++)
            dst[(d0 + j) * 132 + n] = (unsigned)bf16_rn(vv[j]) * 0x10001u;
    }
    if (t < 128) {
        float s = 0.f, s2 = 0.f;
#pragma unroll
        for (int d4 = 0; d4 < DH_ / 4; d4++) {
            const float4 kk = *(const float4*)&kb[t * DH_ + d4 * 4];
            s += kk.x * kk.x + kk.y * kk.y + kk.z * kk.z + kk.w * kk.w;
            const float4 qq = *(const float4*)&qb[t * DH_ + d4 * 4];
            s2 += qq.x * qq.x + qq.y * qq.y + qq.z * qq.z + qq.w * qq.w;
        }
        sdk[t] = s * diagc;
        sdq[t] = s2 * diagc;
    }
    float kmaxv;
    { const int iv = *slot; kmaxv = __int_as_float((iv >= 0) ? iv : (iv ^ 0x7fffffff)); }
    __syncthreads();

    for (int qd = 0; qd < 4; qd++) {
        {
            const int col = t >> 4, ch2 = t & 15;
            const unsigned* src = P2 + (size_t)(qd * 64 + col) * DH_ + ch2 * 2;
            const unsigned u0 = src[0], u1 = src[1];
            *(uint4*)&sB[col * 136 + ch2 * 8] = make_uint4(u0, u0, u1, u1);
        }
        __syncthreads();
        floatx4 acc[2];
        acc[0] = (floatx4){0.f, 0.f, 0.f, 0.f};
        acc[1] = (floatx4){0.f, 0.f, 0.f, 0.f};
#pragma unroll
        for (int ks = 0; ks < 4; ks++) {
            const short8 af = *(const short8*)&sA[(wg * 16 + l16) * 136 + ks * 32 + quad * 8];
            short8 bf[2];
#pragma unroll
            for (int ctl = 0; ctl < 2; ctl++)
                bf[ctl] = *(const short8*)&sB[((2 * wh + ctl) * 16 + l16) * 136 + ks * 32 + quad * 8];
#pragma unroll
            for (int ctl = 0; ctl < 2; ctl++)
                acc[ctl] = __builtin_amdgcn_mfma_f32_16x16x32_bf16(af, bf[ctl], acc[ctl], 0, 0, 0);
        }
        unsigned* kpT = (unsigned*)sBig;
        float kc[2];
#pragma unroll
        for (int ctl = 0; ctl < 2; ctl++) {
            float kcl = 0.f;
            unsigned pk[4];
#pragma unroll
            for (int i = 0; i < 4; i++) {
                const int n = wg * 16 + quad * 4 + i;
                const float kp = ratio * (exp2f((acc[ctl][i] * nrm - sdk[n] - kmaxv) * LOG2E) + 1e-4f);
                kcl += kp;
                pk[i] = split_pack(kp);
            }
            *(uint4*)&kpT[((2 * wh + ctl) * 16 + l16) * 132 + wg * 16 + quad * 4] =
                make_uint4(pk[0], pk[1], pk[2], pk[3]);
            kc[ctl] = kcl;
        }
#pragma unroll
        for (int ctl = 0; ctl < 2; ctl++) {
            kc[ctl] += __shfl_xor(kc[ctl], 16, 64);
            kc[ctl] += __shfl_xor(kc[ctl], 32, 64);
        }
        if (quad == 0) {
            sksP[w * 32 + l16] = kc[0];
            sksP[w * 32 + 16 + l16] = kc[1];
        }
        __syncthreads();
        if (t < 64) {
            float s = 0.f;
#pragma unroll
            for (int wg2 = 0; wg2 < 8; wg2++)
                s += sksP[((t >> 5) * 8 + wg2) * 32 + (t & 31)];
            sksum[qd * 64 + t] = s;
        }
        if (w < 8) {
            const int mt = w & 3, dt = w >> 2;
            floatx4 cacc = (floatx4){0.f, 0.f, 0.f, 0.f};
#pragma unroll
            for (int ks = 0; ks < 8; ks++) {
                const short8 a = *(const short8*)&sBig[(mt * 16 + l16) * 264 + ks * 32 + quad * 8];
                const short8 bvv = *(const short8*)&sV[(dt * 16 + l16) * 264 + ks * 32 + quad * 8];
                cacc = __builtin_amdgcn_mfma_f32_16x16x32_bf16(a, bvv, cacc, 0, 0, 0);
            }
            unsigned* ctxB = (unsigned*)sCtx;
            unsigned pk[4];
#pragma unroll
            for (int i = 0; i < 4; i++) pk[i] = (unsigned)bf16_rn(cacc[i]) * 0x10001u;
            *(uint4*)&ctxB[(dt * 16 + l16) * 260 + qd * 64 + mt * 16 + quad * 4] =
                make_uint4(pk[0], pk[1], pk[2], pk[3]);
        }
        __syncthreads();
    }

    if (t < 512) {
        const int row = t >> 2, seg = t & 3;
        const float* src = qb + row * DH_ + seg * 8;
        float vv[8];
        *(float4*)&vv[0] = *(const float4*)&src[0];
        *(float4*)&vv[4] = *(const float4*)&src[4];
#pragma unroll
        for (int p = 0; p < 4; p++) {
            unsigned hh0, ll0, hh1, ll1;
            split2(vv[2 * p], hh0, ll0); split2(vv[2 * p + 1], hh1, ll1);
            *(uint4*)&sA[row * 136 + seg * 32 + p * 8] = make_uint4(hh0, ll0, hh1, ll1);
        }
    }

    floatx4 adq[4][2];
#pragma unroll
    for (int qd = 0; qd < 4; qd++) {
        {
            const int col = t >> 4, ch2 = t & 15;
            const unsigned* src = P2 + (size_t)(qd * 64 + col) * DH_ + ch2 * 2;
            const unsigned u0 = src[0], u1 = src[1];
            *(uint4*)&sB[col * 136 + ch2 * 8] = make_uint4(u0, u0, u1, u1);
        }
        __syncthreads();
        adq[qd][0] = (floatx4){0.f, 0.f, 0.f, 0.f};
        adq[qd][1] = (floatx4){0.f, 0.f, 0.f, 0.f};
#pragma unroll
        for (int ks = 0; ks < 4; ks++) {
            const short8 bf = *(const short8*)&sA[(wg * 16 + l16) * 136 + ks * 32 + quad * 8];
            short8 af[2];
#pragma unroll
            for (int mtl = 0; mtl < 2; mtl++)
                af[mtl] = *(const short8*)&sB[((2 * wh + mtl) * 16 + l16) * 136 + ks * 32 + quad * 8];
#pragma unroll
            for (int mtl = 0; mtl < 2; mtl++)
                adq[qd][mtl] = __builtin_amdgcn_mfma_f32_16x16x32_bf16(af[mtl], bf, adq[qd][mtl], 0, 0, 0);
        }
        __syncthreads();
    }

    const int nq = wg * 16 + l16;
    {
        float mxn = -INFINITY;
#pragma unroll
        for (int qd = 0; qd < 4; qd++)
#pragma unroll
            for (int mtl = 0; mtl < 2; mtl++)
#pragma unroll
                for (int i = 0; i < 4; i++) mxn = fmaxf(mxn, adq[qd][mtl][i]);
        mxn = fmaxf(mxn, __shfl_xor(mxn, 16, 64));
        mxn = fmaxf(mxn, __shfl_xor(mxn, 32, 64));
        if (quad == 0) smaxP[wh * 128 + nq] = mxn;
    }
    __syncthreads();
    const float dmq = sdq[nq] + fmaxf(smaxP[nq], smaxP[128 + nq]) * nrm;

    floatx4 oacc = (floatx4){0.f, 0.f, 0.f, 0.f};
    float dp = 0.f;
#pragma unroll
    for (int qd = 0; qd < 4; qd++) {
        unsigned* qpA = (unsigned*)sBig;
#pragma unroll
        for (int mtl = 0; mtl < 2; mtl++) {
            unsigned pk[4];
#pragma unroll
            for (int i = 0; i < 4; i++) {
                const float qp = ratio * (exp2f((adq[qd][mtl][i] * nrm - dmq) * LOG2E) + 1e-4f);
                dp += qp * sksum[qd * 64 + (2 * wh + mtl) * 16 + quad * 4 + i];
                pk[i] = split_pack(qp);
            }
            *(uint4*)&qpA[nq * 68 + (2 * wh + mtl) * 16 + quad * 4] = make_uint4(pk[0], pk[1], pk[2], pk[3]);
        }
        __syncthreads();
#pragma unroll
        for (int ks = 0; ks < 4; ks++) {
            const short8 af = *(const short8*)&sBig[(wg * 16 + l16) * 136 + ks * 32 + quad * 8];
            const short8 bf = *(const short8*)&sCtx[(wh * 16 + l16) * 520 + qd * 128 + ks * 32 + quad * 8];
            oacc = __builtin_amdgcn_mfma_f32_16x16x32_bf16(af, bf, oacc, 0, 0, 0);
        }
        __syncthreads();
    }
    dp += __shfl_xor(dp, 16, 64);
    dp += __shfl_xor(dp, 32, 64);
    if (quad == 0) sdenP[wh * 128 + nq] = dp;
    __syncthreads();

#pragma unroll
    for (int i = 0; i < 4; i++) {
        const int n = wg * 16 + quad * 4 + i;
        const float inv = 1.0f / (sdenP[n] + sdenP[128 + n]);
        outp[((size_t)b * S_ + n) * D_ + hh * DH_ + wh * 16 + l16] = oacc[i] * inv;
    }
}

// ---------- classification head ----------
__global__ void __launch_bounds__(256) k_head(
    const float* __restrict__ hfin, const float* __restrict__ h1w, const float* __restrict__ h1b,
    const float* __restrict__ h2w, const float* __restrict__ h2b,
    const float* __restrict__ ow, const float* __restrict__ ob, float* __restrict__ outp)
{
    __shared__ float c0[D_];
    __shared__ float c1[2 * HID_];
    __shared__ float sred[4];
    const int t = threadIdx.x;
    const int b = blockIdx.x;
    c0[t] = hfin[(size_t)b * S_ * D_ + t];
    __syncthreads();
#pragma unroll
    for (int half = 0; half < 2; half++) {
        const int j = half * 256 + t;
        float a = h1b[j];
        const float* w = h1w + (size_t)j * D_;
        for (int d = 0; d < D_; d += 4) {
            const float4 w4 = *(const float4*)&w[d];
            const float4 x4 = *(const float4*)&c0[d];
            a += x4.x * w4.x + x4.y * w4.y + x4.z * w4.z + x4.w * w4.w;
        }
        c1[j] = (a >= 0.f) ? a : 0.2f * a;
    }
    __syncthreads();
    float a2 = h2b[t];
    const float* w2 = h2w + (size_t)t * (2 * HID_);
    for (int j = 0; j < 2 * HID_; j += 4) {
        const float4 w4 = *(const float4*)&w2[j];
        const float4 x4 = *(const float4*)&c1[j];
        a2 += x4.x * w4.x + x4.y * w4.y + x4.z * w4.z + x4.w * w4.w;
    }
    const float c2 = (a2 >= 0.f) ? a2 : 0.2f * a2;
    const float s = blk_sum(c2 * ow[t], sred);
    if (t == 0) outp[b] = s + ob[0];
}

extern "C" void kernel_launch(void* const* d_in, const int* in_sizes, int n_in,
                              void* d_out, int out_size, void* d_ws, size_t ws_size,
                              hipStream_t stream)
{
    const float* x     = (const float*)d_in[0];
    const int*   mask  = (const int*)d_in[1];
    const float* emb_w = (const float*)d_in[2];
    const float* emb_b = (const float*)d_in[3];
    const float* Wq    = (const float*)d_in[4];
    const float* bq    = (const float*)d_in[5];
    const float* Wk    = (const float*)d_in[6];
    const float* bk    = (const float*)d_in[7];
    const float* Wv    = (const float*)d_in[8];
    const float* bv    = (const float*)d_in[9];
    const float* Wo    = (const float*)d_in[10];
    const float* bo    = (const float*)d_in[11];
    const float* proj  = (const float*)d_in[12];
    const float* n1w   = (const float*)d_in[13];
    const float* n1b   = (const float*)d_in[14];
    const float* n2w   = (const float*)d_in[15];
    const float* n2b   = (const float*)d_in[16];
    const float* f1w   = (const float*)d_in[17];
    const float* f1b   = (const float*)d_in[18];
    const float* f2w   = (const float*)d_in[19];
    const float* f2b   = (const float*)d_in[20];
    const float* h1w   = (const float*)d_in[21];
    const float* h1b   = (const float*)d_in[22];
    const float* h2w   = (const float*)d_in[23];
    const float* h2b   = (const float*)d_in[24];
    const float* ow    = (const float*)d_in[25];
    const float* ob    = (const float*)d_in[26];

    const size_t BSD = (size_t)B_ * S_ * D_;
    float* A = (float*)d_ws;
    float* Q = A + BSD;
    float* K = Q + BSD;
    float* V = K + BSD;
    float* T = K;                              // post-LN1 alias (K dead after attn)
    unsigned* WT = (unsigned*)(V + BSD);       // expanded weights: 6 x L x 131072 uints
    const size_t WTt = (size_t)L_ * 131072;    // uints per tensor
    const size_t WMx = 131072;                 // uints per matrix
    unsigned* P2 = WT + 6 * WTt;               // compact split proj: L x 256 x 32 uints
    int* slots = (int*)(P2 + (size_t)L_ * M_ * DH_);

    k_wconvx<<<512, 256, 0, stream>>>(Wq,  WT + 0 * WTt);
    k_wconvx<<<512, 256, 0, stream>>>(Wk,  WT + 1 * WTt);
    k_wconvx<<<512, 256, 0, stream>>>(Wv,  WT + 2 * WTt);
    k_wconvx<<<512, 256, 0, stream>>>(Wo,  WT + 3 * WTt);
    k_wconvx<<<512, 256, 0, stream>>>(f1w, WT + 4 * WTt);
    k_wconvx<<<512, 256, 0, stream>>>(f2w, WT + 5 * WTt);
    k_wconv<<<32, 256, 0, stream>>>(proj, P2);
    k_reset<<<1, 64, 0, stream>>>(slots);

    const int GB = B_ * S_ / 64;               // 512 blocks per GEMM
    const int DB = B_ * H_ * S_ / 64 * 2;      // 8192 blocks for k_dmax
    const size_t ATTN_LDS = 143360;            // 140 KB dynamic LDS

    k_embed<<<B_ * S_ * D_ / 256, 256, 0, stream>>>(x, emb_w, emb_b, A);
    for (int l = 0; l < L_; l++) {
        const unsigned* P2l = P2 + (size_t)l * M_ * DH_;
        k_gemm<0><<<GB, 256, 0, stream>>>(A, WT + 0 * WTt + l * WMx, bq + l * D_, nullptr, nullptr, nullptr, Q);
        k_gemm<0><<<GB, 256, 0, stream>>>(A, WT + 1 * WTt + l * WMx, bk + l * D_, nullptr, nullptr, nullptr, K);
        k_gemm<1><<<GB, 256, 0, stream>>>(A, WT + 2 * WTt + l * WMx, bv + l * D_, nullptr, nullptr, mask, V);
        k_dmax<<<DB, 256, 0, stream>>>(K, P2l, slots + l);
        k_attn2<<<B_ * H_, 1024, ATTN_LDS, stream>>>(Q, K, V, P2l, slots + l, A);
        k_gemm<2><<<GB, 256, 0, stream>>>(A, WT + 3 * WTt + l * WMx, bo + l * D_, n1w + l * D_, n1b + l * D_, nullptr, T);
        k_gemm<3><<<GB, 256, 0, stream>>>(T, WT + 4 * WTt + l * WMx, f1b + l * HID_, nullptr, nullptr, nullptr, Q);
        k_gemm<2><<<GB, 256, 0, stream>>>(Q, WT + 5 * WTt + l * WMx, f2b + l * D_, n2w + l * D_, n2b + l * D_, nullptr, A);
    }
    k_head<<<B_, 256, 0, stream>>>(A, h1w, h1b, h2w, h2b, ow, ob, (float*)d_out);
}

// Round 12
// 2181.437 us; speedup vs baseline: 1.7048x; 1.7048x over previous
//
#include <hip/hip_runtime.h>
#include <math.h>

#define B_ 256
#define N_ 127
#define S_ 128
#define NDIM_ 3
#define D_ 256
#define H_ 8
#define DH_ 32
#define M_ 256
#define HID_ 256
#define L_ 4
#define LOG2E 1.44269504088896340736f

typedef __attribute__((ext_vector_type(8))) short short8;
typedef __attribute__((ext_vector_type(4))) float floatx4;

// ---------- bf16 split helpers ----------
__device__ __forceinline__ ushort bf16_rn(float x) {
    unsigned u = __float_as_uint(x);
    u = (u + 0x7fffu + ((u >> 16) & 1u)) >> 16;
    return (ushort)u;
}
__device__ __forceinline__ void split2(float x, unsigned& hh, unsigned& ll) {
    const ushort h = bf16_rn(x);
    const float r = x - __uint_as_float(((unsigned)h) << 16);
    const ushort l = bf16_rn(r);
    hh = (unsigned)h * 0x10001u;
    ll = (unsigned)l * 0x10001u;
}
__device__ __forceinline__ unsigned split_pack(float x) {
    const ushort h = bf16_rn(x);
    const float r = x - __uint_as_float(((unsigned)h) << 16);
    const ushort l = bf16_rn(r);
    return (unsigned)h | ((unsigned)l << 16);
}

// ---------- block reductions ----------
__device__ __forceinline__ float blk_sum(float v, float* sred) {
#pragma unroll
    for (int o = 32; o > 0; o >>= 1) v += __shfl_xor(v, o, 64);
    if ((threadIdx.x & 63) == 0) sred[threadIdx.x >> 6] = v;
    __syncthreads();
    v = sred[0] + sred[1] + sred[2] + sred[3];
    __syncthreads();
    return v;
}

// ---------- embedding ----------
__global__ void k_embed(const float* __restrict__ x, const float* __restrict__ ew,
                        const float* __restrict__ eb, float* __restrict__ h) {
    const int idx = blockIdx.x * 256 + threadIdx.x;
    const int d = idx & (D_ - 1);
    const int n = (idx >> 8) & (S_ - 1);
    const int b = idx >> 15;
    float val = 0.f;
    if (n > 0) {
        const float* xr = x + ((size_t)b * N_ + (n - 1)) * NDIM_;
        val = eb[d] + xr[0] * ew[d * 3 + 0] + xr[1] * ew[d * 3 + 1] + xr[2] * ew[d * 3 + 2];
    }
    h[idx] = val;
}

// ---------- weight pre-split (compact): fp32 -> uint [h|l<<16] ----------
__global__ void __launch_bounds__(256) k_wconv(const float* __restrict__ src, unsigned* __restrict__ dst) {
    const int idx = (blockIdx.x * 256 + threadIdx.x) * 4;
    const float4 w4 = *(const float4*)&src[idx];
    const float v[4] = {w4.x, w4.y, w4.z, w4.w};
    unsigned u[4];
#pragma unroll
    for (int i = 0; i < 4; i++) u[i] = split_pack(v[i]);
    *(uint4*)&dst[idx] = make_uint4(u[0], u[1], u[2], u[3]);
}

// ---------- MFMA bf16x2-split GEMM: C[64 x 256] per block, K2 = 1024 ----------
// R10-proven structure (compact W2 staged via LDS) + double-buffered tiles:
// single barrier per s-step; stage of step s+1 issues before step-s MFMAs.
template<int EPI>
__global__ void __launch_bounds__(256) k_gemm(
    const float* __restrict__ A, const unsigned* __restrict__ W2,
    const float* __restrict__ bias, const float* __restrict__ g1,
    const float* __restrict__ g2, const int* __restrict__ mask,
    float* __restrict__ out)
{
    __shared__ ushort A2s[2][4 * 64 * 8];     // [buf][c][row][8]
    __shared__ ushort W2s[2][4 * 256 * 8];    // [buf][c][col][8]
    __shared__ float sredA[64][2], sredB[64][2];
    const int t = threadIdx.x;
    const int w = t >> 6, lane = t & 63;
    const int quad = lane >> 4, l16 = lane & 15;
    const int rowbase = 32 * (w >> 1), colbase = 128 * (w & 1);
    const int row0 = blockIdx.x * 64;

    floatx4 acc[2][8];
#pragma unroll
    for (int rt = 0; rt < 2; rt++)
#pragma unroll
        for (int ct = 0; ct < 8; ct++) acc[rt][ct] = (floatx4){0.f, 0.f, 0.f, 0.f};

    const int srow = t >> 2, skq = t & 3;
    const float* Arow = A + (size_t)(row0 + srow) * D_ + skq * 2;
    const unsigned* Wrow = W2 + (size_t)t * 256;

    // prologue: stage s=0 into buf 0
    {
        const float2 a2 = *(const float2*)(Arow);
        unsigned hh0, ll0, hh1, ll1;
        split2(a2.x, hh0, ll0); split2(a2.y, hh1, ll1);
        *(uint4*)&A2s[0][skq * 512 + srow * 8] = make_uint4(hh0, ll0, hh1, ll1);
        const uint4* wp = (const uint4*)(Wrow);
        const uint4 w0 = wp[0], w1 = wp[1];
        *(uint4*)&W2s[0][0 * 2048 + t * 8] = make_uint4(w0.x, w0.x, w0.y, w0.y);
        *(uint4*)&W2s[0][1 * 2048 + t * 8] = make_uint4(w0.z, w0.z, w0.w, w0.w);
        *(uint4*)&W2s[0][2 * 2048 + t * 8] = make_uint4(w1.x, w1.x, w1.y, w1.y);
        *(uint4*)&W2s[0][3 * 2048 + t * 8] = make_uint4(w1.z, w1.z, w1.w, w1.w);
    }
    __syncthreads();

    for (int s = 0; s < 32; s++) {
        const int p = s & 1;
        if (s + 1 < 32) {   // prefetch-stage s+1 into buf p^1 (consumed-at-last-barrier)
            const float2 a2 = *(const float2*)(Arow + (s + 1) * 8);
            unsigned hh0, ll0, hh1, ll1;
            split2(a2.x, hh0, ll0); split2(a2.y, hh1, ll1);
            *(uint4*)&A2s[p ^ 1][skq * 512 + srow * 8] = make_uint4(hh0, ll0, hh1, ll1);
            const uint4* wp = (const uint4*)(Wrow + (s + 1) * 8);
            const uint4 w0 = wp[0], w1 = wp[1];
            *(uint4*)&W2s[p ^ 1][0 * 2048 + t * 8] = make_uint4(w0.x, w0.x, w0.y, w0.y);
            *(uint4*)&W2s[p ^ 1][1 * 2048 + t * 8] = make_uint4(w0.z, w0.z, w0.w, w0.w);
            *(uint4*)&W2s[p ^ 1][2 * 2048 + t * 8] = make_uint4(w1.x, w1.x, w1.y, w1.y);
            *(uint4*)&W2s[p ^ 1][3 * 2048 + t * 8] = make_uint4(w1.z, w1.z, w1.w, w1.w);
        }
        short8 af[2], bf[8];
#pragma unroll
        for (int rt = 0; rt < 2; rt++)
            af[rt] = *(const short8*)&A2s[p][quad * 512 + (rowbase + 16 * rt + l16) * 8];
#pragma unroll
        for (int ct = 0; ct < 8; ct++)
            bf[ct] = *(const short8*)&W2s[p][quad * 2048 + (colbase + 16 * ct + l16) * 8];
#pragma unroll
        for (int rt = 0; rt < 2; rt++)
#pragma unroll
            for (int ct = 0; ct < 8; ct++)
                acc[rt][ct] = __builtin_amdgcn_mfma_f32_16x16x32_bf16(af[rt], bf[ct], acc[rt][ct], 0, 0, 0);
        __syncthreads();   // buf p consumed; buf p^1 writes visible for next step
    }

    int colv[8]; float bv[8];
#pragma unroll
    for (int ct = 0; ct < 8; ct++) { colv[ct] = colbase + 16 * ct + l16; bv[ct] = bias[colv[ct]]; }

    if (EPI <= 1) {
        const int b = row0 >> 7;
#pragma unroll
        for (int rt = 0; rt < 2; rt++)
#pragma unroll
        for (int i = 0; i < 4; i++) {
            const int rl = rowbase + 16 * rt + quad * 4 + i;
            const int n = (row0 + rl) & (S_ - 1);
            float keep = 1.f;
            if (EPI == 1) keep = (n == 0) ? 1.f : (mask[b * N_ + n - 1] ? 0.f : 1.f);
#pragma unroll
            for (int ct = 0; ct < 8; ct++) {
                float c = acc[rt][ct][i] + bv[ct];
                if (EPI == 1) c *= keep;
                const int col = colv[ct];
                out[(((size_t)b * H_ + (col >> 5)) * S_ + n) * DH_ + (col & 31)] = c;
            }
        }
    } else if (EPI == 2) {
        float gv[8], bbv[8];
#pragma unroll
        for (int ct = 0; ct < 8; ct++) { gv[ct] = g1[colv[ct]]; bbv[ct] = g2[colv[ct]]; }
#pragma unroll
        for (int rt = 0; rt < 2; rt++)
#pragma unroll
        for (int i = 0; i < 4; i++) {
            const int rl = rowbase + 16 * rt + quad * 4 + i;
            float s = 0.f, s2 = 0.f;
#pragma unroll
            for (int ct = 0; ct < 8; ct++) {
                const float c = acc[rt][ct][i] + bv[ct];
                s += c; s2 += c * c;
            }
#pragma unroll
            for (int o = 8; o > 0; o >>= 1) { s += __shfl_xor(s, o, 64); s2 += __shfl_xor(s2, o, 64); }
            if (l16 == 0) { sredA[rl][w & 1] = s; sredB[rl][w & 1] = s2; }
        }
        __syncthreads();
#pragma unroll
        for (int rt = 0; rt < 2; rt++)
#pragma unroll
        for (int i = 0; i < 4; i++) {
            const int rl = rowbase + 16 * rt + quad * 4 + i;
            const float s = sredA[rl][0] + sredA[rl][1];
            const float s2 = sredB[rl][0] + sredB[rl][1];
            const float mu = s * (1.f / D_);
            const float rs = rsqrtf(s2 * (1.f / D_) - mu * mu + 1e-5f);
#pragma unroll
            for (int ct = 0; ct < 8; ct++) {
                const float c = acc[rt][ct][i] + bv[ct];
                out[(size_t)(row0 + rl) * D_ + colv[ct]] = (c - mu) * rs * gv[ct] + bbv[ct];
            }
        }
    } else {
#pragma unroll
        for (int rt = 0; rt < 2; rt++)
#pragma unroll
        for (int i = 0; i < 4; i++) {
            const int rl = rowbase + 16 * rt + quad * 4 + i;
#pragma unroll
            for (int ct = 0; ct < 8; ct++) {
                const float c = acc[rt][ct][i] + bv[ct];
                out[(size_t)(row0 + rl) * D_ + colv[ct]] = (c >= 0.f) ? c : 0.2f * c;
            }
        }
    }
}

// ---------- reset kmax slots ----------
__global__ void k_reset(int* slots) {
    if (threadIdx.x < 4) {
        const int i = __float_as_int(-INFINITY);
        slots[threadIdx.x] = (i >= 0) ? i : (i ^ 0x7fffffff);
    }
}

// ---------- MFMA global k-max (proven) ----------
__global__ void __launch_bounds__(256) k_dmax(
    const float* __restrict__ kg, const unsigned* __restrict__ P2, int* __restrict__ slot)
{
    __shared__ __align__(16) ushort A2s[64 * 136];
    __shared__ __align__(16) ushort Ps[128 * 136];
    __shared__ float sred[4];
    const int t = threadIdx.x;
    const size_t row0 = (size_t)(blockIdx.x >> 1) * 64;
    const int m0 = (blockIdx.x & 1) * 128;
    {
        const int row = t >> 2, kq = (t & 3) * 8;
        const float* src = kg + (row0 + row) * DH_ + kq;
        const float4 f0 = *(const float4*)src;
        const float4 f1 = *(const float4*)(src + 4);
        const float vv[8] = {f0.x, f0.y, f0.z, f0.w, f1.x, f1.y, f1.z, f1.w};
#pragma unroll
        for (int i = 0; i < 4; i++) {
            unsigned hh0, ll0, hh1, ll1;
            split2(vv[2 * i], hh0, ll0); split2(vv[2 * i + 1], hh1, ll1);
            *(uint4*)&A2s[row * 136 + ((t & 3) * 4 + i) * 8] = make_uint4(hh0, ll0, hh1, ll1);
        }
    }
    {
        const int col = t >> 1;
        const unsigned* src = P2 + (m0 + col) * DH_ + (t & 1) * 16;
#pragma unroll
        for (int i = 0; i < 8; i++) {
            const unsigned u0 = src[2 * i], u1 = src[2 * i + 1];
            *(uint4*)&Ps[col * 136 + ((t & 1) * 8 + i) * 8] = make_uint4(u0, u0, u1, u1);
        }
    }
    __syncthreads();
    const int w = t >> 6, lane = t & 63, quad = lane >> 4, l16 = lane & 15;
    floatx4 acc[4][2];
#pragma unroll
    for (int rt = 0; rt < 4; rt++)
#pragma unroll
        for (int ct = 0; ct < 2; ct++) acc[rt][ct] = (floatx4){0.f, 0.f, 0.f, 0.f};
#pragma unroll
    for (int kk = 0; kk < 4; kk++) {
        short8 af[4], bf[2];
#pragma unroll
        for (int rt = 0; rt < 4; rt++)
            af[rt] = *(const short8*)&A2s[(rt * 16 + l16) * 136 + (kk * 4 + quad) * 8];
#pragma unroll
        for (int ct = 0; ct < 2; ct++)
            bf[ct] = *(const short8*)&Ps[((w * 2 + ct) * 16 + l16) * 136 + (kk * 4 + quad) * 8];
#pragma unroll
        for (int rt = 0; rt < 4; rt++)
#pragma unroll
            for (int ct = 0; ct < 2; ct++)
                acc[rt][ct] = __builtin_amdgcn_mfma_f32_16x16x32_bf16(af[rt], bf[ct], acc[rt][ct], 0, 0, 0);
    }
    float mx = -INFINITY;
#pragma unroll
    for (int rt = 0; rt < 4; rt++)
#pragma unroll
        for (int ct = 0; ct < 2; ct++)
#pragma unroll
            for (int i = 0; i < 4; i++) mx = fmaxf(mx, acc[rt][ct][i]);
#pragma unroll
    for (int o = 32; o > 0; o >>= 1) mx = fmaxf(mx, __shfl_xor(mx, o, 64));
    if (lane == 0) sred[w] = mx;
    __syncthreads();
    if (t == 0) {
        const float m4 = fmaxf(fmaxf(sred[0], sred[1]), fmaxf(sred[2], sred[3]))
                       * 0.42044820762685725f;
        const int i = __float_as_int(m4);
        atomicMax(slot, (i >= 0) ? i : (i ^ 0x7fffffff));
    }
}

// ---------- full-MFMA performer attention, 1024 threads (16 waves), 140 KB LDS ----------
__global__ void __launch_bounds__(1024) k_attn2(
    const float* __restrict__ qg, const float* __restrict__ kg, const float* __restrict__ vg,
    const unsigned* __restrict__ P2, const int* __restrict__ slot,
    float* __restrict__ outp)
{
    extern __shared__ char smem[];
    ushort* sA    = (ushort*)(smem);            // [128][136]: K-split, then Q-split
    ushort* sB    = (ushort*)(smem + 34816);    // [64][136]: P-quarter {h,l,h,l}
    ushort* sBig  = (ushort*)(smem + 52224);    // kpT [64][264] / qpA [128][136]
    ushort* sV    = (ushort*)(smem + 87040);    // [32][264]: v dup
    ushort* sCtx  = (ushort*)(smem + 103936);   // [32][520]: ctx dup
    float* sdk    = (float*)(smem + 137216);    // [128]
    float* sdq    = (float*)(smem + 137728);    // [128]
    float* smaxP  = (float*)(smem + 138240);    // [2][128]
    float* sdenP  = (float*)(smem + 139264);    // [2][128]
    float* sksum  = (float*)(smem + 140288);    // [256]
    float* sksP   = (float*)(smem + 141312);    // [16][32]

    const int bh = blockIdx.x;
    const int b = bh >> 3, hh = bh & 7;
    const int t = threadIdx.x;
    const int w = t >> 6, lane = t & 63, quad = lane >> 4, l16 = lane & 15;
    const int wg = w & 7, wh = w >> 3;
    const float* kb = kg + (size_t)bh * S_ * DH_;
    const float* qb = qg + (size_t)bh * S_ * DH_;
    const float* vb = vg + (size_t)bh * S_ * DH_;
    const float nrm = 0.42044820762685725f;
    const float diagc = 0.5f * nrm * nrm;
    const float ratio = 0.0625f;

    if (t < 512) {
        const int row = t >> 2, seg = t & 3;
        const float* src = kb + row * DH_ + seg * 8;
        float vv[8];
        *(float4*)&vv[0] = *(const float4*)&src[0];
        *(float4*)&vv[4] = *(const float4*)&src[4];
#pragma unroll
        for (int p = 0; p < 4; p++) {
            unsigned hh0, ll0, hh1, ll1;
            split2(vv[2 * p], hh0, ll0); split2(vv[2 * p + 1], hh1, ll1);
            *(uint4*)&sA[row * 136 + seg * 32 + p * 8] = make_uint4(hh0, ll0, hh1, ll1);
        }
    } else {
        const int tt2 = t - 512;
        const int n = tt2 & 127, d0 = (tt2 >> 7) * 8;
        const float* src = vb + n * DH_ + d0;
        float vv[8];
        *(float4*)&vv[0] = *(const float4*)&src[0];
        *(float4*)&vv[4] = *(const float4*)&src[4];
        unsigned* dst = (unsigned*)sV;
#pragma unroll
        for (int j = 0; j < 8; j++)
            dst[(d0 + j) * 132 + n] = (unsigned)bf16_rn(vv[j]) * 0x10001u;
    }
    if (t < 128) {
        float s = 0.f, s2 = 0.f;
#pragma unroll
        for (int d4 = 0; d4 < DH_ / 4; d4++) {
            const float4 kk = *(const float4*)&kb[t * DH_ + d4 * 4];
            s += kk.x * kk.x + kk.y * kk.y + kk.z * kk.z + kk.w * kk.w;
            const float4 qq = *(const float4*)&qb[t * DH_ + d4 * 4];
            s2 += qq.x * qq.x + qq.y * qq.y + qq.z * qq.z + qq.w * qq.w;
        }
        sdk[t] = s * diagc;
        sdq[t] = s2 * diagc;
    }
    float kmaxv;
    { const int iv = *slot; kmaxv = __int_as_float((iv >= 0) ? iv : (iv ^ 0x7fffffff)); }
    __syncthreads();

    for (int qd = 0; qd < 4; qd++) {
        {
            const int col = t >> 4, ch2 = t & 15;
            const unsigned* src = P2 + (size_t)(qd * 64 + col) * DH_ + ch2 * 2;
            const unsigned u0 = src[0], u1 = src[1];
            *(uint4*)&sB[col * 136 + ch2 * 8] = make_uint4(u0, u0, u1, u1);
        }
        __syncthreads();
        floatx4 acc[2];
        acc[0] = (floatx4){0.f, 0.f, 0.f, 0.f};
        acc[1] = (floatx4){0.f, 0.f, 0.f, 0.f};
#pragma unroll
        for (int ks = 0; ks < 4; ks++) {
            const short8 af = *(const short8*)&sA[(wg * 16 + l16) * 136 + ks * 32 + quad * 8];
            short8 bf[2];
#pragma unroll
            for (int ctl = 0; ctl < 2; ctl++)
                bf[ctl] = *(const short8*)&sB[((2 * wh + ctl) * 16 + l16) * 136 + ks * 32 + quad * 8];
#pragma unroll
            for (int ctl = 0; ctl < 2; ctl++)
                acc[ctl] = __builtin_amdgcn_mfma_f32_16x16x32_bf16(af, bf[ctl], acc[ctl], 0, 0, 0);
        }
        unsigned* kpT = (unsigned*)sBig;
        float kc[2];
#pragma unroll
        for (int ctl = 0; ctl < 2; ctl++) {
            float kcl = 0.f;
            unsigned pk[4];
#pragma unroll
            for (int i = 0; i < 4; i++) {
                const int n = wg * 16 + quad * 4 + i;
                const float kp = ratio * (exp2f((acc[ctl][i] * nrm - sdk[n] - kmaxv) * LOG2E) + 1e-4f);
                kcl += kp;
                pk[i] = split_pack(kp);
            }
            *(uint4*)&kpT[((2 * wh + ctl) * 16 + l16) * 132 + wg * 16 + quad * 4] =
                make_uint4(pk[0], pk[1], pk[2], pk[3]);
            kc[ctl] = kcl;
        }
#pragma unroll
        for (int ctl = 0; ctl < 2; ctl++) {
            kc[ctl] += __shfl_xor(kc[ctl], 16, 64);
            kc[ctl] += __shfl_xor(kc[ctl], 32, 64);
        }
        if (quad == 0) {
            sksP[w * 32 + l16] = kc[0];
            sksP[w * 32 + 16 + l16] = kc[1];
        }
        __syncthreads();
        if (t < 64) {
            float s = 0.f;
#pragma unroll
            for (int wg2 = 0; wg2 < 8; wg2++)
                s += sksP[((t >> 5) * 8 + wg2) * 32 + (t & 31)];
            sksum[qd * 64 + t] = s;
        }
        if (w < 8) {
            const int mt = w & 3, dt = w >> 2;
            floatx4 cacc = (floatx4){0.f, 0.f, 0.f, 0.f};
#pragma unroll
            for (int ks = 0; ks < 8; ks++) {
                const short8 a = *(const short8*)&sBig[(mt * 16 + l16) * 264 + ks * 32 + quad * 8];
                const short8 bvv = *(const short8*)&sV[(dt * 16 + l16) * 264 + ks * 32 + quad * 8];
                cacc = __builtin_amdgcn_mfma_f32_16x16x32_bf16(a, bvv, cacc, 0, 0, 0);
            }
            unsigned* ctxB = (unsigned*)sCtx;
            unsigned pk[4];
#pragma unroll
            for (int i = 0; i < 4; i++) pk[i] = (unsigned)bf16_rn(cacc[i]) * 0x10001u;
            *(uint4*)&ctxB[(dt * 16 + l16) * 260 + qd * 64 + mt * 16 + quad * 4] =
                make_uint4(pk[0], pk[1], pk[2], pk[3]);
        }
        __syncthreads();
    }

    if (t < 512) {
        const int row = t >> 2, seg = t & 3;
        const float* src = qb + row * DH_ + seg * 8;
        float vv[8];
        *(float4*)&vv[0] = *(const float4*)&src[0];
        *(float4*)&vv[4] = *(const float4*)&src[4];
#pragma unroll
        for (int p = 0; p < 4; p++) {
            unsigned hh0, ll0, hh1, ll1;
            split2(vv[2 * p], hh0, ll0); split2(vv[2 * p + 1], hh1, ll1);
            *(uint4*)&sA[row * 136 + seg * 32 + p * 8] = make_uint4(hh0, ll0, hh1, ll1);
        }
    }

    floatx4 adq[4][2];
#pragma unroll
    for (int qd = 0; qd < 4; qd++) {
        {
            const int col = t >> 4, ch2 = t & 15;
            const unsigned* src = P2 + (size_t)(qd * 64 + col) * DH_ + ch2 * 2;
            const unsigned u0 = src[0], u1 = src[1];
            *(uint4*)&sB[col * 136 + ch2 * 8] = make_uint4(u0, u0, u1, u1);
        }
        __syncthreads();
        adq[qd][0] = (floatx4){0.f, 0.f, 0.f, 0.f};
        adq[qd][1] = (floatx4){0.f, 0.f, 0.f, 0.f};
#pragma unroll
        for (int ks = 0; ks < 4; ks++) {
            const short8 bf = *(const short8*)&sA[(wg * 16 + l16) * 136 + ks * 32 + quad * 8];
            short8 af[2];
#pragma unroll
            for (int mtl = 0; mtl < 2; mtl++)
                af[mtl] = *(const short8*)&sB[((2 * wh + mtl) * 16 + l16) * 136 + ks * 32 + quad * 8];
#pragma unroll
            for (int mtl = 0; mtl < 2; mtl++)
                adq[qd][mtl] = __builtin_amdgcn_mfma_f32_16x16x32_bf16(af[mtl], bf, adq[qd][mtl], 0, 0, 0);
        }
        __syncthreads();
    }

    const int nq = wg * 16 + l16;
    {
        float mxn = -INFINITY;
#pragma unroll
        for (int qd = 0; qd < 4; qd++)
#pragma unroll
            for (int mtl = 0; mtl < 2; mtl++)
#pragma unroll
                for (int i = 0; i < 4; i++) mxn = fmaxf(mxn, adq[qd][mtl][i]);
        mxn = fmaxf(mxn, __shfl_xor(mxn, 16, 64));
        mxn = fmaxf(mxn, __shfl_xor(mxn, 32, 64));
        if (quad == 0) smaxP[wh * 128 + nq] = mxn;
    }
    __syncthreads();
    const float dmq = sdq[nq] + fmaxf(smaxP[nq], smaxP[128 + nq]) * nrm;

    floatx4 oacc = (floatx4){0.f, 0.f, 0.f, 0.f};
    float dp = 0.f;
#pragma unroll
    for (int qd = 0; qd < 4; qd++) {
        unsigned* qpA = (unsigned*)sBig;
#pragma unroll
        for (int mtl = 0; mtl < 2; mtl++) {
            unsigned pk[4];
#pragma unroll
            for (int i = 0; i < 4; i++) {
                const float qp = ratio * (exp2f((adq[qd][mtl][i] * nrm - dmq) * LOG2E) + 1e-4f);
                dp += qp * sksum[qd * 64 + (2 * wh + mtl) * 16 + quad * 4 + i];
                pk[i] = split_pack(qp);
            }
            *(uint4*)&qpA[nq * 68 + (2 * wh + mtl) * 16 + quad * 4] = make_uint4(pk[0], pk[1], pk[2], pk[3]);
        }
        __syncthreads();
#pragma unroll
        for (int ks = 0; ks < 4; ks++) {
            const short8 af = *(const short8*)&sBig[(wg * 16 + l16) * 136 + ks * 32 + quad * 8];
            const short8 bf = *(const short8*)&sCtx[(wh * 16 + l16) * 520 + qd * 128 + ks * 32 + quad * 8];
            oacc = __builtin_amdgcn_mfma_f32_16x16x32_bf16(af, bf, oacc, 0, 0, 0);
        }
        __syncthreads();
    }
    dp += __shfl_xor(dp, 16, 64);
    dp += __shfl_xor(dp, 32, 64);
    if (quad == 0) sdenP[wh * 128 + nq] = dp;
    __syncthreads();

#pragma unroll
    for (int i = 0; i < 4; i++) {
        const int n = wg * 16 + quad * 4 + i;
        const float inv = 1.0f / (sdenP[n] + sdenP[128 + n]);
        outp[((size_t)b * S_ + n) * D_ + hh * DH_ + wh * 16 + l16] = oacc[i] * inv;
    }
}

// ---------- classification head ----------
__global__ void __launch_bounds__(256) k_head(
    const float* __restrict__ hfin, const float* __restrict__ h1w, const float* __restrict__ h1b,
    const float* __restrict__ h2w, const float* __restrict__ h2b,
    const float* __restrict__ ow, const float* __restrict__ ob, float* __restrict__ outp)
{
    __shared__ float c0[D_];
    __shared__ float c1[2 * HID_];
    __shared__ float sred[4];
    const int t = threadIdx.x;
    const int b = blockIdx.x;
    c0[t] = hfin[(size_t)b * S_ * D_ + t];
    __syncthreads();
#pragma unroll
    for (int half = 0; half < 2; half++) {
        const int j = half * 256 + t;
        float a = h1b[j];
        const float* w = h1w + (size_t)j * D_;
        for (int d = 0; d < D_; d += 4) {
            const float4 w4 = *(const float4*)&w[d];
            const float4 x4 = *(const float4*)&c0[d];
            a += x4.x * w4.x + x4.y * w4.y + x4.z * w4.z + x4.w * w4.w;
        }
        c1[j] = (a >= 0.f) ? a : 0.2f * a;
    }
    __syncthreads();
    float a2 = h2b[t];
    const float* w2 = h2w + (size_t)t * (2 * HID_);
    for (int j = 0; j < 2 * HID_; j += 4) {
        const float4 w4 = *(const float4*)&w2[j];
        const float4 x4 = *(const float4*)&c1[j];
        a2 += x4.x * w4.x + x4.y * w4.y + x4.z * w4.z + x4.w * w4.w;
    }
    const float c2 = (a2 >= 0.f) ? a2 : 0.2f * a2;
    const float s = blk_sum(c2 * ow[t], sred);
    if (t == 0) outp[b] = s + ob[0];
}

extern "C" void kernel_launch(void* const* d_in, const int* in_sizes, int n_in,
                              void* d_out, int out_size, void* d_ws, size_t ws_size,
                              hipStream_t stream)
{
    const float* x     = (const float*)d_in[0];
    const int*   mask  = (const int*)d_in[1];
    const float* emb_w = (const float*)d_in[2];
    const float* emb_b = (const float*)d_in[3];
    const float* Wq    = (const float*)d_in[4];
    const float* bq    = (const float*)d_in[5];
    const float* Wk    = (const float*)d_in[6];
    const float* bk    = (const float*)d_in[7];
    const float* Wv    = (const float*)d_in[8];
    const float* bv    = (const float*)d_in[9];
    const float* Wo    = (const float*)d_in[10];
    const float* bo    = (const float*)d_in[11];
    const float* proj  = (const float*)d_in[12];
    const float* n1w   = (const float*)d_in[13];
    const float* n1b   = (const float*)d_in[14];
    const float* n2w   = (const float*)d_in[15];
    const float* n2b   = (const float*)d_in[16];
    const float* f1w   = (const float*)d_in[17];
    const float* f1b   = (const float*)d_in[18];
    const float* f2w   = (const float*)d_in[19];
    const float* f2b   = (const float*)d_in[20];
    const float* h1w   = (const float*)d_in[21];
    const float* h1b   = (const float*)d_in[22];
    const float* h2w   = (const float*)d_in[23];
    const float* h2b   = (const float*)d_in[24];
    const float* ow    = (const float*)d_in[25];
    const float* ob    = (const float*)d_in[26];

    const size_t BSD = (size_t)B_ * S_ * D_;
    float* A = (float*)d_ws;
    float* Q = A + BSD;
    float* K = Q + BSD;
    float* V = K + BSD;
    float* T = K;                              // post-LN1 alias (K dead after attn)
    unsigned* W2 = (unsigned*)(V + BSD);       // compact split weights: 6 x L x 65536 uints
    const size_t WT = (size_t)L_ * 256 * 256;
    const size_t WM = (size_t)256 * 256;
    unsigned* P2 = W2 + 6 * WT;                // compact split proj: L x 256 x 32 uints
    int* slots = (int*)(P2 + (size_t)L_ * M_ * DH_);

    k_wconv<<<256, 256, 0, stream>>>(Wq,  W2 + 0 * WT);
    k_wconv<<<256, 256, 0, stream>>>(Wk,  W2 + 1 * WT);
    k_wconv<<<256, 256, 0, stream>>>(Wv,  W2 + 2 * WT);
    k_wconv<<<256, 256, 0, stream>>>(Wo,  W2 + 3 * WT);
    k_wconv<<<256, 256, 0, stream>>>(f1w, W2 + 4 * WT);
    k_wconv<<<256, 256, 0, stream>>>(f2w, W2 + 5 * WT);
    k_wconv<<<32, 256, 0, stream>>>(proj, P2);
    k_reset<<<1, 64, 0, stream>>>(slots);

    const int GB = B_ * S_ / 64;               // 512 blocks per GEMM
    const int DB = B_ * H_ * S_ / 64 * 2;      // 8192 blocks for k_dmax
    const size_t ATTN_LDS = 143360;            // 140 KB dynamic LDS

    k_embed<<<B_ * S_ * D_ / 256, 256, 0, stream>>>(x, emb_w, emb_b, A);
    for (int l = 0; l < L_; l++) {
        const unsigned* P2l = P2 + (size_t)l * M_ * DH_;
        k_gemm<0><<<GB, 256, 0, stream>>>(A, W2 + 0 * WT + l * WM, bq + l * D_, nullptr, nullptr, nullptr, Q);
        k_gemm<0><<<GB, 256, 0, stream>>>(A, W2 + 1 * WT + l * WM, bk + l * D_, nullptr, nullptr, nullptr, K);
        k_gemm<1><<<GB, 256, 0, stream>>>(A, W2 + 2 * WT + l * WM, bv + l * D_, nullptr, nullptr, mask, V);
        k_dmax<<<DB, 256, 0, stream>>>(K, P2l, slots + l);
        k_attn2<<<B_ * H_, 1024, ATTN_LDS, stream>>>(Q, K, V, P2l, slots + l, A);
        k_gemm<2><<<GB, 256, 0, stream>>>(A, W2 + 3 * WT + l * WM, bo + l * D_, n1w + l * D_, n1b + l * D_, nullptr, T);
        k_gemm<3><<<GB, 256, 0, stream>>>(T, W2 + 4 * WT + l * WM, f1b + l * HID_, nullptr, nullptr, nullptr, Q);
        k_gemm<2><<<GB, 256, 0, stream>>>(Q, W2 + 5 * WT + l * WM, f2b + l * D_, n2w + l * D_, n2b + l * D_, nullptr, A);
    }
    k_head<<<B_, 256, 0, stream>>>(A, h1w, h1b, h2w, h2b, ow, ob, (float*)d_out);
}

// Round 13
// 2054.375 us; speedup vs baseline: 1.8103x; 1.0618x over previous
//
#include <hip/hip_runtime.h>
#include <math.h>

#define B_ 256
#define N_ 127
#define S_ 128
#define NDIM_ 3
#define D_ 256
#define H_ 8
#define DH_ 32
#define M_ 256
#define HID_ 256
#define L_ 4
#define LOG2E 1.44269504088896340736f

typedef __attribute__((ext_vector_type(8))) short short8;
typedef __attribute__((ext_vector_type(4))) float floatx4;

// ---------- bf16 split helpers ----------
__device__ __forceinline__ ushort bf16_rn(float x) {
    unsigned u = __float_as_uint(x);
    u = (u + 0x7fffu + ((u >> 16) & 1u)) >> 16;
    return (ushort)u;
}
__device__ __forceinline__ void split2(float x, unsigned& hh, unsigned& ll) {
    const ushort h = bf16_rn(x);
    const float r = x - __uint_as_float(((unsigned)h) << 16);
    const ushort l = bf16_rn(r);
    hh = (unsigned)h * 0x10001u;
    ll = (unsigned)l * 0x10001u;
}
__device__ __forceinline__ unsigned split_pack(float x) {
    const ushort h = bf16_rn(x);
    const float r = x - __uint_as_float(((unsigned)h) << 16);
    const ushort l = bf16_rn(r);
    return (unsigned)h | ((unsigned)l << 16);
}

// ---------- block reductions ----------
__device__ __forceinline__ float blk_sum(float v, float* sred) {
#pragma unroll
    for (int o = 32; o > 0; o >>= 1) v += __shfl_xor(v, o, 64);
    if ((threadIdx.x & 63) == 0) sred[threadIdx.x >> 6] = v;
    __syncthreads();
    v = sred[0] + sred[1] + sred[2] + sred[3];
    __syncthreads();
    return v;
}

// ---------- embedding ----------
__global__ void k_embed(const float* __restrict__ x, const float* __restrict__ ew,
                        const float* __restrict__ eb, float* __restrict__ h) {
    const int idx = blockIdx.x * 256 + threadIdx.x;
    const int d = idx & (D_ - 1);
    const int n = (idx >> 8) & (S_ - 1);
    const int b = idx >> 15;
    float val = 0.f;
    if (n > 0) {
        const float* xr = x + ((size_t)b * N_ + (n - 1)) * NDIM_;
        val = eb[d] + xr[0] * ew[d * 3 + 0] + xr[1] * ew[d * 3 + 1] + xr[2] * ew[d * 3 + 2];
    }
    h[idx] = val;
}

// ---------- weight pre-split (compact): fp32 -> uint [h|l<<16] ----------
__global__ void __launch_bounds__(256) k_wconv(const float* __restrict__ src, unsigned* __restrict__ dst) {
    const int idx = (blockIdx.x * 256 + threadIdx.x) * 4;
    const float4 w4 = *(const float4*)&src[idx];
    const float v[4] = {w4.x, w4.y, w4.z, w4.w};
    unsigned u[4];
#pragma unroll
    for (int i = 0; i < 4; i++) u[i] = split_pack(v[i]);
    *(uint4*)&dst[idx] = make_uint4(u[0], u[1], u[2], u[3]);
}

// ---------- MFMA bf16x2-split GEMM: C[64 x 256] per block, 512 threads (8 waves) ----------
// Wave w: row-group w>>2 (32 rows), col-group w&3 (64 cols); acc[2][4].
// Staging: threads 0-255 stage A (R10 pattern); threads 256-511 stage W (R10 pattern).
// 2 blocks/CU x 8 waves = 4 waves/SIMD.
template<int EPI>
__global__ void __launch_bounds__(512, 4) k_gemm(
    const float* __restrict__ A, const unsigned* __restrict__ W2,
    const float* __restrict__ bias, const float* __restrict__ g1,
    const float* __restrict__ g2, const int* __restrict__ mask,
    float* __restrict__ out)
{
    __shared__ ushort A2s[4 * 64 * 8];     // [c][row][8]
    __shared__ ushort W2s[4 * 256 * 8];    // [c][col][8]
    __shared__ float sredA[64][4], sredB[64][4];
    const int t = threadIdx.x;
    const int w = t >> 6, lane = t & 63;
    const int quad = lane >> 4, l16 = lane & 15;
    const int rowbase = 32 * (w >> 2), colbase = 64 * (w & 3);
    const int colg = w & 3;
    const int row0 = blockIdx.x * 64;

    floatx4 acc[2][4];
#pragma unroll
    for (int rt = 0; rt < 2; rt++)
#pragma unroll
        for (int ct = 0; ct < 4; ct++) acc[rt][ct] = (floatx4){0.f, 0.f, 0.f, 0.f};

    const int srow = t >> 2, skq = t & 3;                  // A staging (t < 256)
    const float* Arow = A + (size_t)(row0 + srow) * D_ + skq * 2;
    const int wcol = t - 256;                              // W staging (t >= 256)
    const unsigned* Wrow = W2 + (size_t)wcol * 256;

    for (int s = 0; s < 32; s++) {
        __syncthreads();
        if (t < 256) {
            const float2 a2 = *(const float2*)(Arow + s * 8);
            unsigned hh0, ll0, hh1, ll1;
            split2(a2.x, hh0, ll0); split2(a2.y, hh1, ll1);
            *(uint4*)&A2s[skq * 512 + srow * 8] = make_uint4(hh0, ll0, hh1, ll1);
        } else {
            const uint4* wp = (const uint4*)(Wrow + s * 8);
            const uint4 w0 = wp[0], w1 = wp[1];
            *(uint4*)&W2s[0 * 2048 + wcol * 8] = make_uint4(w0.x, w0.x, w0.y, w0.y);
            *(uint4*)&W2s[1 * 2048 + wcol * 8] = make_uint4(w0.z, w0.z, w0.w, w0.w);
            *(uint4*)&W2s[2 * 2048 + wcol * 8] = make_uint4(w1.x, w1.x, w1.y, w1.y);
            *(uint4*)&W2s[3 * 2048 + wcol * 8] = make_uint4(w1.z, w1.z, w1.w, w1.w);
        }
        __syncthreads();
        short8 af[2], bf[4];
#pragma unroll
        for (int rt = 0; rt < 2; rt++)
            af[rt] = *(const short8*)&A2s[quad * 512 + (rowbase + 16 * rt + l16) * 8];
#pragma unroll
        for (int ct = 0; ct < 4; ct++)
            bf[ct] = *(const short8*)&W2s[quad * 2048 + (colbase + 16 * ct + l16) * 8];
#pragma unroll
        for (int rt = 0; rt < 2; rt++)
#pragma unroll
            for (int ct = 0; ct < 4; ct++)
                acc[rt][ct] = __builtin_amdgcn_mfma_f32_16x16x32_bf16(af[rt], bf[ct], acc[rt][ct], 0, 0, 0);
    }

    int colv[4]; float bv[4];
#pragma unroll
    for (int ct = 0; ct < 4; ct++) { colv[ct] = colbase + 16 * ct + l16; bv[ct] = bias[colv[ct]]; }

    if (EPI <= 1) {
        const int b = row0 >> 7;
#pragma unroll
        for (int rt = 0; rt < 2; rt++)
#pragma unroll
        for (int i = 0; i < 4; i++) {
            const int rl = rowbase + 16 * rt + quad * 4 + i;
            const int n = (row0 + rl) & (S_ - 1);
            float keep = 1.f;
            if (EPI == 1) keep = (n == 0) ? 1.f : (mask[b * N_ + n - 1] ? 0.f : 1.f);
#pragma unroll
            for (int ct = 0; ct < 4; ct++) {
                float c = acc[rt][ct][i] + bv[ct];
                if (EPI == 1) c *= keep;
                const int col = colv[ct];
                out[(((size_t)b * H_ + (col >> 5)) * S_ + n) * DH_ + (col & 31)] = c;
            }
        }
    } else if (EPI == 2) {
        float gv[4], bbv[4];
#pragma unroll
        for (int ct = 0; ct < 4; ct++) { gv[ct] = g1[colv[ct]]; bbv[ct] = g2[colv[ct]]; }
#pragma unroll
        for (int rt = 0; rt < 2; rt++)
#pragma unroll
        for (int i = 0; i < 4; i++) {
            const int rl = rowbase + 16 * rt + quad * 4 + i;
            float s = 0.f, s2 = 0.f;
#pragma unroll
            for (int ct = 0; ct < 4; ct++) {
                const float c = acc[rt][ct][i] + bv[ct];
                s += c; s2 += c * c;
            }
#pragma unroll
            for (int o = 8; o > 0; o >>= 1) { s += __shfl_xor(s, o, 64); s2 += __shfl_xor(s2, o, 64); }
            if (l16 == 0) { sredA[rl][colg] = s; sredB[rl][colg] = s2; }
        }
        __syncthreads();
#pragma unroll
        for (int rt = 0; rt < 2; rt++)
#pragma unroll
        for (int i = 0; i < 4; i++) {
            const int rl = rowbase + 16 * rt + quad * 4 + i;
            const float s = sredA[rl][0] + sredA[rl][1] + sredA[rl][2] + sredA[rl][3];
            const float s2 = sredB[rl][0] + sredB[rl][1] + sredB[rl][2] + sredB[rl][3];
            const float mu = s * (1.f / D_);
            const float rs = rsqrtf(s2 * (1.f / D_) - mu * mu + 1e-5f);
#pragma unroll
            for (int ct = 0; ct < 4; ct++) {
                const float c = acc[rt][ct][i] + bv[ct];
                out[(size_t)(row0 + rl) * D_ + colv[ct]] = (c - mu) * rs * gv[ct] + bbv[ct];
            }
        }
    } else {
#pragma unroll
        for (int rt = 0; rt < 2; rt++)
#pragma unroll
        for (int i = 0; i < 4; i++) {
            const int rl = rowbase + 16 * rt + quad * 4 + i;
#pragma unroll
            for (int ct = 0; ct < 4; ct++) {
                const float c = acc[rt][ct][i] + bv[ct];
                out[(size_t)(row0 + rl) * D_ + colv[ct]] = (c >= 0.f) ? c : 0.2f * c;
            }
        }
    }
}

// ---------- reset kmax slots ----------
__global__ void k_reset(int* slots) {
    if (threadIdx.x < 4) {
        const int i = __float_as_int(-INFINITY);
        slots[threadIdx.x] = (i >= 0) ? i : (i ^ 0x7fffffff);
    }
}

// ---------- MFMA global k-max (proven) ----------
__global__ void __launch_bounds__(256) k_dmax(
    const float* __restrict__ kg, const unsigned* __restrict__ P2, int* __restrict__ slot)
{
    __shared__ __align__(16) ushort A2s[64 * 136];
    __shared__ __align__(16) ushort Ps[128 * 136];
    __shared__ float sred[4];
    const int t = threadIdx.x;
    const size_t row0 = (size_t)(blockIdx.x >> 1) * 64;
    const int m0 = (blockIdx.x & 1) * 128;
    {
        const int row = t >> 2, kq = (t & 3) * 8;
        const float* src = kg + (row0 + row) * DH_ + kq;
        const float4 f0 = *(const float4*)src;
        const float4 f1 = *(const float4*)(src + 4);
        const float vv[8] = {f0.x, f0.y, f0.z, f0.w, f1.x, f1.y, f1.z, f1.w};
#pragma unroll
        for (int i = 0; i < 4; i++) {
            unsigned hh0, ll0, hh1, ll1;
            split2(vv[2 * i], hh0, ll0); split2(vv[2 * i + 1], hh1, ll1);
            *(uint4*)&A2s[row * 136 + ((t & 3) * 4 + i) * 8] = make_uint4(hh0, ll0, hh1, ll1);
        }
    }
    {
        const int col = t >> 1;
        const unsigned* src = P2 + (m0 + col) * DH_ + (t & 1) * 16;
#pragma unroll
        for (int i = 0; i < 8; i++) {
            const unsigned u0 = src[2 * i], u1 = src[2 * i + 1];
            *(uint4*)&Ps[col * 136 + ((t & 1) * 8 + i) * 8] = make_uint4(u0, u0, u1, u1);
        }
    }
    __syncthreads();
    const int w = t >> 6, lane = t & 63, quad = lane >> 4, l16 = lane & 15;
    floatx4 acc[4][2];
#pragma unroll
    for (int rt = 0; rt < 4; rt++)
#pragma unroll
        for (int ct = 0; ct < 2; ct++) acc[rt][ct] = (floatx4){0.f, 0.f, 0.f, 0.f};
#pragma unroll
    for (int kk = 0; kk < 4; kk++) {
        short8 af[4], bf[2];
#pragma unroll
        for (int rt = 0; rt < 4; rt++)
            af[rt] = *(const short8*)&A2s[(rt * 16 + l16) * 136 + (kk * 4 + quad) * 8];
#pragma unroll
        for (int ct = 0; ct < 2; ct++)
            bf[ct] = *(const short8*)&Ps[((w * 2 + ct) * 16 + l16) * 136 + (kk * 4 + quad) * 8];
#pragma unroll
        for (int rt = 0; rt < 4; rt++)
#pragma unroll
            for (int ct = 0; ct < 2; ct++)
                acc[rt][ct] = __builtin_amdgcn_mfma_f32_16x16x32_bf16(af[rt], bf[ct], acc[rt][ct], 0, 0, 0);
    }
    float mx = -INFINITY;
#pragma unroll
    for (int rt = 0; rt < 4; rt++)
#pragma unroll
        for (int ct = 0; ct < 2; ct++)
#pragma unroll
            for (int i = 0; i < 4; i++) mx = fmaxf(mx, acc[rt][ct][i]);
#pragma unroll
    for (int o = 32; o > 0; o >>= 1) mx = fmaxf(mx, __shfl_xor(mx, o, 64));
    if (lane == 0) sred[w] = mx;
    __syncthreads();
    if (t == 0) {
        const float m4 = fmaxf(fmaxf(sred[0], sred[1]), fmaxf(sred[2], sred[3]))
                       * 0.42044820762685725f;
        const int i = __float_as_int(m4);
        atomicMax(slot, (i >= 0) ? i : (i ^ 0x7fffffff));
    }
}

// ---------- full-MFMA performer attention, 1024 threads (16 waves), 140 KB LDS ----------
__global__ void __launch_bounds__(1024) k_attn2(
    const float* __restrict__ qg, const float* __restrict__ kg, const float* __restrict__ vg,
    const unsigned* __restrict__ P2, const int* __restrict__ slot,
    float* __restrict__ outp)
{
    extern __shared__ char smem[];
    ushort* sA    = (ushort*)(smem);            // [128][136]: K-split, then Q-split
    ushort* sB    = (ushort*)(smem + 34816);    // [64][136]: P-quarter {h,l,h,l}
    ushort* sBig  = (ushort*)(smem + 52224);    // kpT [64][264] / qpA [128][136]
    ushort* sV    = (ushort*)(smem + 87040);    // [32][264]: v dup
    ushort* sCtx  = (ushort*)(smem + 103936);   // [32][520]: ctx dup
    float* sdk    = (float*)(smem + 137216);    // [128]
    float* sdq    = (float*)(smem + 137728);    // [128]
    float* smaxP  = (float*)(smem + 138240);    // [2][128]
    float* sdenP  = (float*)(smem + 139264);    // [2][128]
    float* sksum  = (float*)(smem + 140288);    // [256]
    float* sksP   = (float*)(smem + 141312);    // [16][32]

    const int bh = blockIdx.x;
    const int b = bh >> 3, hh = bh & 7;
    const int t = threadIdx.x;
    const int w = t >> 6, lane = t & 63, quad = lane >> 4, l16 = lane & 15;
    const int wg = w & 7, wh = w >> 3;
    const float* kb = kg + (size_t)bh * S_ * DH_;
    const float* qb = qg + (size_t)bh * S_ * DH_;
    const float* vb = vg + (size_t)bh * S_ * DH_;
    const float nrm = 0.42044820762685725f;
    const float diagc = 0.5f * nrm * nrm;
    const float ratio = 0.0625f;

    if (t < 512) {
        const int row = t >> 2, seg = t & 3;
        const float* src = kb + row * DH_ + seg * 8;
        float vv[8];
        *(float4*)&vv[0] = *(const float4*)&src[0];
        *(float4*)&vv[4] = *(const float4*)&src[4];
#pragma unroll
        for (int p = 0; p < 4; p++) {
            unsigned hh0, ll0, hh1, ll1;
            split2(vv[2 * p], hh0, ll0); split2(vv[2 * p + 1], hh1, ll1);
            *(uint4*)&sA[row * 136 + seg * 32 + p * 8] = make_uint4(hh0, ll0, hh1, ll1);
        }
    } else {
        const int tt2 = t - 512;
        const int n = tt2 & 127, d0 = (tt2 >> 7) * 8;
        const float* src = vb + n * DH_ + d0;
        float vv[8];
        *(float4*)&vv[0] = *(const float4*)&src[0];
        *(float4*)&vv[4] = *(const float4*)&src[4];
        unsigned* dst = (unsigned*)sV;
#pragma unroll
        for (int j = 0; j < 8; j++)
            dst[(d0 + j) * 132 + n] = (unsigned)bf16_rn(vv[j]) * 0x10001u;
    }
    if (t < 128) {
        float s = 0.f, s2 = 0.f;
#pragma unroll
        for (int d4 = 0; d4 < DH_ / 4; d4++) {
            const float4 kk = *(const float4*)&kb[t * DH_ + d4 * 4];
            s += kk.x * kk.x + kk.y * kk.y + kk.z * kk.z + kk.w * kk.w;
            const float4 qq = *(const float4*)&qb[t * DH_ + d4 * 4];
            s2 += qq.x * qq.x + qq.y * qq.y + qq.z * qq.z + qq.w * qq.w;
        }
        sdk[t] = s * diagc;
        sdq[t] = s2 * diagc;
    }
    float kmaxv;
    { const int iv = *slot; kmaxv = __int_as_float((iv >= 0) ? iv : (iv ^ 0x7fffffff)); }
    __syncthreads();

    for (int qd = 0; qd < 4; qd++) {
        {
            const int col = t >> 4, ch2 = t & 15;
            const unsigned* src = P2 + (size_t)(qd * 64 + col) * DH_ + ch2 * 2;
            const unsigned u0 = src[0], u1 = src[1];
            *(uint4*)&sB[col * 136 + ch2 * 8] = make_uint4(u0, u0, u1, u1);
        }
        __syncthreads();
        floatx4 acc[2];
        acc[0] = (floatx4){0.f, 0.f, 0.f, 0.f};
        acc[1] = (floatx4){0.f, 0.f, 0.f, 0.f};
#pragma unroll
        for (int ks = 0; ks < 4; ks++) {
            const short8 af = *(const short8*)&sA[(wg * 16 + l16) * 136 + ks * 32 + quad * 8];
            short8 bf[2];
#pragma unroll
            for (int ctl = 0; ctl < 2; ctl++)
                bf[ctl] = *(const short8*)&sB[((2 * wh + ctl) * 16 + l16) * 136 + ks * 32 + quad * 8];
#pragma unroll
            for (int ctl = 0; ctl < 2; ctl++)
                acc[ctl] = __builtin_amdgcn_mfma_f32_16x16x32_bf16(af, bf[ctl], acc[ctl], 0, 0, 0);
        }
        unsigned* kpT = (unsigned*)sBig;
        float kc[2];
#pragma unroll
        for (int ctl = 0; ctl < 2; ctl++) {
            float kcl = 0.f;
            unsigned pk[4];
#pragma unroll
            for (int i = 0; i < 4; i++) {
                const int n = wg * 16 + quad * 4 + i;
                const float kp = ratio * (exp2f((acc[ctl][i] * nrm - sdk[n] - kmaxv) * LOG2E) + 1e-4f);
                kcl += kp;
                pk[i] = split_pack(kp);
            }
            *(uint4*)&kpT[((2 * wh + ctl) * 16 + l16) * 132 + wg * 16 + quad * 4] =
                make_uint4(pk[0], pk[1], pk[2], pk[3]);
            kc[ctl] = kcl;
        }
#pragma unroll
        for (int ctl = 0; ctl < 2; ctl++) {
            kc[ctl] += __shfl_xor(kc[ctl], 16, 64);
            kc[ctl] += __shfl_xor(kc[ctl], 32, 64);
        }
        if (quad == 0) {
            sksP[w * 32 + l16] = kc[0];
            sksP[w * 32 + 16 + l16] = kc[1];
        }
        __syncthreads();
        if (t < 64) {
            float s = 0.f;
#pragma unroll
            for (int wg2 = 0; wg2 < 8; wg2++)
                s += sksP[((t >> 5) * 8 + wg2) * 32 + (t & 31)];
            sksum[qd * 64 + t] = s;
        }
        if (w < 8) {
            const int mt = w & 3, dt = w >> 2;
            floatx4 cacc = (floatx4){0.f, 0.f, 0.f, 0.f};
#pragma unroll
            for (int ks = 0; ks < 8; ks++) {
                const short8 a = *(const short8*)&sBig[(mt * 16 + l16) * 264 + ks * 32 + quad * 8];
                const short8 bvv = *(const short8*)&sV[(dt * 16 + l16) * 264 + ks * 32 + quad * 8];
                cacc = __builtin_amdgcn_mfma_f32_16x16x32_bf16(a, bvv, cacc, 0, 0, 0);
            }
            unsigned* ctxB = (unsigned*)sCtx;
            unsigned pk[4];
#pragma unroll
            for (int i = 0; i < 4; i++) pk[i] = (unsigned)bf16_rn(cacc[i]) * 0x10001u;
            *(uint4*)&ctxB[(dt * 16 + l16) * 260 + qd * 64 + mt * 16 + quad * 4] =
                make_uint4(pk[0], pk[1], pk[2], pk[3]);
        }
        __syncthreads();
    }

    if (t < 512) {
        const int row = t >> 2, seg = t & 3;
        const float* src = qb + row * DH_ + seg * 8;
        float vv[8];
        *(float4*)&vv[0] = *(const float4*)&src[0];
        *(float4*)&vv[4] = *(const float4*)&src[4];
#pragma unroll
        for (int p = 0; p < 4; p++) {
            unsigned hh0, ll0, hh1, ll1;
            split2(vv[2 * p], hh0, ll0); split2(vv[2 * p + 1], hh1, ll1);
            *(uint4*)&sA[row * 136 + seg * 32 + p * 8] = make_uint4(hh0, ll0, hh1, ll1);
        }
    }

    floatx4 adq[4][2];
#pragma unroll
    for (int qd = 0; qd < 4; qd++) {
        {
            const int col = t >> 4, ch2 = t & 15;
            const unsigned* src = P2 + (size_t)(qd * 64 + col) * DH_ + ch2 * 2;
            const unsigned u0 = src[0], u1 = src[1];
            *(uint4*)&sB[col * 136 + ch2 * 8] = make_uint4(u0, u0, u1, u1);
        }
        __syncthreads();
        adq[qd][0] = (floatx4){0.f, 0.f, 0.f, 0.f};
        adq[qd][1] = (floatx4){0.f, 0.f, 0.f, 0.f};
#pragma unroll
        for (int ks = 0; ks < 4; ks++) {
            const short8 bf = *(const short8*)&sA[(wg * 16 + l16) * 136 + ks * 32 + quad * 8];
            short8 af[2];
#pragma unroll
            for (int mtl = 0; mtl < 2; mtl++)
                af[mtl] = *(const short8*)&sB[((2 * wh + mtl) * 16 + l16) * 136 + ks * 32 + quad * 8];
#pragma unroll
            for (int mtl = 0; mtl < 2; mtl++)
                adq[qd][mtl] = __builtin_amdgcn_mfma_f32_16x16x32_bf16(af[mtl], bf, adq[qd][mtl], 0, 0, 0);
        }
        __syncthreads();
    }

    const int nq = wg * 16 + l16;
    {
        float mxn = -INFINITY;
#pragma unroll
        for (int qd = 0; qd < 4; qd++)
#pragma unroll
            for (int mtl = 0; mtl < 2; mtl++)
#pragma unroll
                for (int i = 0; i < 4; i++) mxn = fmaxf(mxn, adq[qd][mtl][i]);
        mxn = fmaxf(mxn, __shfl_xor(mxn, 16, 64));
        mxn = fmaxf(mxn, __shfl_xor(mxn, 32, 64));
        if (quad == 0) smaxP[wh * 128 + nq] = mxn;
    }
    __syncthreads();
    const float dmq = sdq[nq] + fmaxf(smaxP[nq], smaxP[128 + nq]) * nrm;

    floatx4 oacc = (floatx4){0.f, 0.f, 0.f, 0.f};
    float dp = 0.f;
#pragma unroll
    for (int qd = 0; qd < 4; qd++) {
        unsigned* qpA = (unsigned*)sBig;
#pragma unroll
        for (int mtl = 0; mtl < 2; mtl++) {
            unsigned pk[4];
#pragma unroll
            for (int i = 0; i < 4; i++) {
                const float qp = ratio * (exp2f((adq[qd][mtl][i] * nrm - dmq) * LOG2E) + 1e-4f);
                dp += qp * sksum[qd * 64 + (2 * wh + mtl) * 16 + quad * 4 + i];
                pk[i] = split_pack(qp);
            }
            *(uint4*)&qpA[nq * 68 + (2 * wh + mtl) * 16 + quad * 4] = make_uint4(pk[0], pk[1], pk[2], pk[3]);
        }
        __syncthreads();
#pragma unroll
        for (int ks = 0; ks < 4; ks++) {
            const short8 af = *(const short8*)&sBig[(wg * 16 + l16) * 136 + ks * 32 + quad * 8];
            const short8 bf = *(const short8*)&sCtx[(wh * 16 + l16) * 520 + qd * 128 + ks * 32 + quad * 8];
            oacc = __builtin_amdgcn_mfma_f32_16x16x32_bf16(af, bf, oacc, 0, 0, 0);
        }
        __syncthreads();
    }
    dp += __shfl_xor(dp, 16, 64);
    dp += __shfl_xor(dp, 32, 64);
    if (quad == 0) sdenP[wh * 128 + nq] = dp;
    __syncthreads();

#pragma unroll
    for (int i = 0; i < 4; i++) {
        const int n = wg * 16 + quad * 4 + i;
        const float inv = 1.0f / (sdenP[n] + sdenP[128 + n]);
        outp[((size_t)b * S_ + n) * D_ + hh * DH_ + wh * 16 + l16] = oacc[i] * inv;
    }
}

// ---------- classification head ----------
__global__ void __launch_bounds__(256) k_head(
    const float* __restrict__ hfin, const float* __restrict__ h1w, const float* __restrict__ h1b,
    const float* __restrict__ h2w, const float* __restrict__ h2b,
    const float* __restrict__ ow, const float* __restrict__ ob, float* __restrict__ outp)
{
    __shared__ float c0[D_];
    __shared__ float c1[2 * HID_];
    __shared__ float sred[4];
    const int t = threadIdx.x;
    const int b = blockIdx.x;
    c0[t] = hfin[(size_t)b * S_ * D_ + t];
    __syncthreads();
#pragma unroll
    for (int half = 0; half < 2; half++) {
        const int j = half * 256 + t;
        float a = h1b[j];
        const float* w = h1w + (size_t)j * D_;
        for (int d = 0; d < D_; d += 4) {
            const float4 w4 = *(const float4*)&w[d];
            const float4 x4 = *(const float4*)&c0[d];
            a += x4.x * w4.x + x4.y * w4.y + x4.z * w4.z + x4.w * w4.w;
        }
        c1[j] = (a >= 0.f) ? a : 0.2f * a;
    }
    __syncthreads();
    float a2 = h2b[t];
    const float* w2 = h2w + (size_t)t * (2 * HID_);
    for (int j = 0; j < 2 * HID_; j += 4) {
        const float4 w4 = *(const float4*)&w2[j];
        const float4 x4 = *(const float4*)&c1[j];
        a2 += x4.x * w4.x + x4.y * w4.y + x4.z * w4.z + x4.w * w4.w;
    }
    const float c2 = (a2 >= 0.f) ? a2 : 0.2f * a2;
    const float s = blk_sum(c2 * ow[t], sred);
    if (t == 0) outp[b] = s + ob[0];
}

extern "C" void kernel_launch(void* const* d_in, const int* in_sizes, int n_in,
                              void* d_out, int out_size, void* d_ws, size_t ws_size,
                              hipStream_t stream)
{
    const float* x     = (const float*)d_in[0];
    const int*   mask  = (const int*)d_in[1];
    const float* emb_w = (const float*)d_in[2];
    const float* emb_b = (const float*)d_in[3];
    const float* Wq    = (const float*)d_in[4];
    const float* bq    = (const float*)d_in[5];
    const float* Wk    = (const float*)d_in[6];
    const float* bk    = (const float*)d_in[7];
    const float* Wv    = (const float*)d_in[8];
    const float* bv    = (const float*)d_in[9];
    const float* Wo    = (const float*)d_in[10];
    const float* bo    = (const float*)d_in[11];
    const float* proj  = (const float*)d_in[12];
    const float* n1w   = (const float*)d_in[13];
    const float* n1b   = (const float*)d_in[14];
    const float* n2w   = (const float*)d_in[15];
    const float* n2b   = (const float*)d_in[16];
    const float* f1w   = (const float*)d_in[17];
    const float* f1b   = (const float*)d_in[18];
    const float* f2w   = (const float*)d_in[19];
    const float* f2b   = (const float*)d_in[20];
    const float* h1w   = (const float*)d_in[21];
    const float* h1b   = (const float*)d_in[22];
    const float* h2w   = (const float*)d_in[23];
    const float* h2b   = (const float*)d_in[24];
    const float* ow    = (const float*)d_in[25];
    const float* ob    = (const float*)d_in[26];

    const size_t BSD = (size_t)B_ * S_ * D_;
    float* A = (float*)d_ws;
    float* Q = A + BSD;
    float* K = Q + BSD;
    float* V = K + BSD;
    float* T = K;                              // post-LN1 alias (K dead after attn)
    unsigned* W2 = (unsigned*)(V + BSD);       // compact split weights: 6 x L x 65536 uints
    const size_t WT = (size_t)L_ * 256 * 256;
    const size_t WM = (size_t)256 * 256;
    unsigned* P2 = W2 + 6 * WT;                // compact split proj: L x 256 x 32 uints
    int* slots = (int*)(P2 + (size_t)L_ * M_ * DH_);

    k_wconv<<<256, 256, 0, stream>>>(Wq,  W2 + 0 * WT);
    k_wconv<<<256, 256, 0, stream>>>(Wk,  W2 + 1 * WT);
    k_wconv<<<256, 256, 0, stream>>>(Wv,  W2 + 2 * WT);
    k_wconv<<<256, 256, 0, stream>>>(Wo,  W2 + 3 * WT);
    k_wconv<<<256, 256, 0, stream>>>(f1w, W2 + 4 * WT);
    k_wconv<<<256, 256, 0, stream>>>(f2w, W2 + 5 * WT);
    k_wconv<<<32, 256, 0, stream>>>(proj, P2);
    k_reset<<<1, 64, 0, stream>>>(slots);

    const int GB = B_ * S_ / 64;               // 512 blocks per GEMM
    const int DB = B_ * H_ * S_ / 64 * 2;      // 8192 blocks for k_dmax
    const size_t ATTN_LDS = 143360;            // 140 KB dynamic LDS

    k_embed<<<B_ * S_ * D_ / 256, 256, 0, stream>>>(x, emb_w, emb_b, A);
    for (int l = 0; l < L_; l++) {
        const unsigned* P2l = P2 + (size_t)l * M_ * DH_;
        k_gemm<0><<<GB, 512, 0, stream>>>(A, W2 + 0 * WT + l * WM, bq + l * D_, nullptr, nullptr, nullptr, Q);
        k_gemm<0><<<GB, 512, 0, stream>>>(A, W2 + 1 * WT + l * WM, bk + l * D_, nullptr, nullptr, nullptr, K);
        k_gemm<1><<<GB, 512, 0, stream>>>(A, W2 + 2 * WT + l * WM, bv + l * D_, nullptr, nullptr, mask, V);
        k_dmax<<<DB, 256, 0, stream>>>(K, P2l, slots + l);
        k_attn2<<<B_ * H_, 1024, ATTN_LDS, stream>>>(Q, K, V, P2l, slots + l, A);
        k_gemm<2><<<GB, 512, 0, stream>>>(A, W2 + 3 * WT + l * WM, bo + l * D_, n1w + l * D_, n1b + l * D_, nullptr, T);
        k_gemm<3><<<GB, 512, 0, stream>>>(T, W2 + 4 * WT + l * WM, f1b + l * HID_, nullptr, nullptr, nullptr, Q);
        k_gemm<2><<<GB, 512, 0, stream>>>(Q, W2 + 5 * WT + l * WM, f2b + l * D_, n2w + l * D_, n2b + l * D_, nullptr, A);
    }
    k_head<<<B_, 256, 0, stream>>>(A, h1w, h1b, h2w, h2b, ow, ob, (float*)d_out);
}

// Round 14
// 2019.604 us; speedup vs baseline: 1.8414x; 1.0172x over previous
//
#include <hip/hip_runtime.h>
#include <math.h>

#define B_ 256
#define N_ 127
#define S_ 128
#define NDIM_ 3
#define D_ 256
#define H_ 8
#define DH_ 32
#define M_ 256
#define HID_ 256
#define L_ 4
#define LOG2E 1.44269504088896340736f

typedef __attribute__((ext_vector_type(8))) short short8;
typedef __attribute__((ext_vector_type(4))) float floatx4;

// ---------- bf16 split helpers ----------
__device__ __forceinline__ ushort bf16_rn(float x) {
    unsigned u = __float_as_uint(x);
    u = (u + 0x7fffu + ((u >> 16) & 1u)) >> 16;
    return (ushort)u;
}
__device__ __forceinline__ void split2(float x, unsigned& hh, unsigned& ll) {
    const ushort h = bf16_rn(x);
    const float r = x - __uint_as_float(((unsigned)h) << 16);
    const ushort l = bf16_rn(r);
    hh = (unsigned)h * 0x10001u;
    ll = (unsigned)l * 0x10001u;
}
__device__ __forceinline__ unsigned split_pack(float x) {
    const ushort h = bf16_rn(x);
    const float r = x - __uint_as_float(((unsigned)h) << 16);
    const ushort l = bf16_rn(r);
    return (unsigned)h | ((unsigned)l << 16);
}

// ---------- block reductions ----------
__device__ __forceinline__ float blk_sum(float v, float* sred) {
#pragma unroll
    for (int o = 32; o > 0; o >>= 1) v += __shfl_xor(v, o, 64);
    if ((threadIdx.x & 63) == 0) sred[threadIdx.x >> 6] = v;
    __syncthreads();
    v = sred[0] + sred[1] + sred[2] + sred[3];
    __syncthreads();
    return v;
}

// ---------- embedding ----------
__global__ void k_embed(const float* __restrict__ x, const float* __restrict__ ew,
                        const float* __restrict__ eb, float* __restrict__ h) {
    const int idx = blockIdx.x * 256 + threadIdx.x;
    const int d = idx & (D_ - 1);
    const int n = (idx >> 8) & (S_ - 1);
    const int b = idx >> 15;
    float val = 0.f;
    if (n > 0) {
        const float* xr = x + ((size_t)b * N_ + (n - 1)) * NDIM_;
        val = eb[d] + xr[0] * ew[d * 3 + 0] + xr[1] * ew[d * 3 + 1] + xr[2] * ew[d * 3 + 2];
    }
    h[idx] = val;
}

// ---------- weight pre-split (compact): fp32 -> uint [h|l<<16] ----------
__global__ void __launch_bounds__(256) k_wconv(const float* __restrict__ src, unsigned* __restrict__ dst) {
    const int idx = (blockIdx.x * 256 + threadIdx.x) * 4;
    const float4 w4 = *(const float4*)&src[idx];
    const float v[4] = {w4.x, w4.y, w4.z, w4.w};
    unsigned u[4];
#pragma unroll
    for (int i = 0; i < 4; i++) u[i] = split_pack(v[i]);
    *(uint4*)&dst[idx] = make_uint4(u[0], u[1], u[2], u[3]);
}

// ---------- MFMA bf16x2-split GEMM, software-pipelined ----------
// 512 threads (8 waves); wave w: row-group w>>2, col-group w&3; acc[2][4].
// Pipeline per s-step: issue global loads for s+1 (regs) -> MFMA from LDS[p]
// -> split+write s+1 to LDS[p^1] -> ONE barrier. vm-wait lands after MFMAs.
template<int EPI>
__global__ void __launch_bounds__(512, 4) k_gemm(
    const float* __restrict__ A, const unsigned* __restrict__ W2,
    const float* __restrict__ bias, const float* __restrict__ g1,
    const float* __restrict__ g2, const int* __restrict__ mask,
    float* __restrict__ out)
{
    __shared__ ushort A2s[2][4 * 64 * 8];     // [buf][c][row][8]
    __shared__ ushort W2s[2][4 * 256 * 8];    // [buf][c][col][8]
    __shared__ float sredA[64][4], sredB[64][4];
    const int t = threadIdx.x;
    const int w = t >> 6, lane = t & 63;
    const int quad = lane >> 4, l16 = lane & 15;
    const int rowbase = 32 * (w >> 2), colbase = 64 * (w & 3);
    const int colg = w & 3;
    const int row0 = blockIdx.x * 64;

    floatx4 acc[2][4];
#pragma unroll
    for (int rt = 0; rt < 2; rt++)
#pragma unroll
        for (int ct = 0; ct < 4; ct++) acc[rt][ct] = (floatx4){0.f, 0.f, 0.f, 0.f};

    const int srow = t >> 2, skq = t & 3;                  // A staging (t < 256)
    const float* Arow = A + (size_t)(row0 + srow) * D_ + skq * 2;
    const int wcol = t - 256;                              // W staging (t >= 256)
    const unsigned* Wrow = W2 + (size_t)wcol * 256;

    // prologue: stage s=0 into buf 0
    if (t < 256) {
        const float2 a2 = *(const float2*)(Arow);
        unsigned hh0, ll0, hh1, ll1;
        split2(a2.x, hh0, ll0); split2(a2.y, hh1, ll1);
        *(uint4*)&A2s[0][skq * 512 + srow * 8] = make_uint4(hh0, ll0, hh1, ll1);
    } else {
        const uint4* wp = (const uint4*)(Wrow);
        const uint4 w0 = wp[0], w1 = wp[1];
        *(uint4*)&W2s[0][0 * 2048 + wcol * 8] = make_uint4(w0.x, w0.x, w0.y, w0.y);
        *(uint4*)&W2s[0][1 * 2048 + wcol * 8] = make_uint4(w0.z, w0.z, w0.w, w0.w);
        *(uint4*)&W2s[0][2 * 2048 + wcol * 8] = make_uint4(w1.x, w1.x, w1.y, w1.y);
        *(uint4*)&W2s[0][3 * 2048 + wcol * 8] = make_uint4(w1.z, w1.z, w1.w, w1.w);
    }
    __syncthreads();

    for (int s = 0; s < 32; s++) {
        const int p = s & 1;
        // (1) issue global loads for s+1 into registers — no use until (3)
        float2 a_nxt;
        uint4 w0_nxt, w1_nxt;
        if (s + 1 < 32) {
            if (t < 256) a_nxt = *(const float2*)(Arow + (s + 1) * 8);
            else {
                const uint4* wp = (const uint4*)(Wrow + (s + 1) * 8);
                w0_nxt = wp[0]; w1_nxt = wp[1];
            }
        }
        // (2) MFMA on step s from LDS[p]
        short8 af[2], bf[4];
#pragma unroll
        for (int rt = 0; rt < 2; rt++)
            af[rt] = *(const short8*)&A2s[p][quad * 512 + (rowbase + 16 * rt + l16) * 8];
#pragma unroll
        for (int ct = 0; ct < 4; ct++)
            bf[ct] = *(const short8*)&W2s[p][quad * 2048 + (colbase + 16 * ct + l16) * 8];
#pragma unroll
        for (int rt = 0; rt < 2; rt++)
#pragma unroll
            for (int ct = 0; ct < 4; ct++)
                acc[rt][ct] = __builtin_amdgcn_mfma_f32_16x16x32_bf16(af[rt], bf[ct], acc[rt][ct], 0, 0, 0);
        // (3) split + write s+1 into LDS[p^1] (free since s-1's MFMAs done pre-barrier)
        if (s + 1 < 32) {
            if (t < 256) {
                unsigned hh0, ll0, hh1, ll1;
                split2(a_nxt.x, hh0, ll0); split2(a_nxt.y, hh1, ll1);
                *(uint4*)&A2s[p ^ 1][skq * 512 + srow * 8] = make_uint4(hh0, ll0, hh1, ll1);
            } else {
                *(uint4*)&W2s[p ^ 1][0 * 2048 + wcol * 8] = make_uint4(w0_nxt.x, w0_nxt.x, w0_nxt.y, w0_nxt.y);
                *(uint4*)&W2s[p ^ 1][1 * 2048 + wcol * 8] = make_uint4(w0_nxt.z, w0_nxt.z, w0_nxt.w, w0_nxt.w);
                *(uint4*)&W2s[p ^ 1][2 * 2048 + wcol * 8] = make_uint4(w1_nxt.x, w1_nxt.x, w1_nxt.y, w1_nxt.y);
                *(uint4*)&W2s[p ^ 1][3 * 2048 + wcol * 8] = make_uint4(w1_nxt.z, w1_nxt.z, w1_nxt.w, w1_nxt.w);
            }
        }
        // (4) single barrier
        __syncthreads();
    }

    int colv[4]; float bv[4];
#pragma unroll
    for (int ct = 0; ct < 4; ct++) { colv[ct] = colbase + 16 * ct + l16; bv[ct] = bias[colv[ct]]; }

    if (EPI <= 1) {
        const int b = row0 >> 7;
#pragma unroll
        for (int rt = 0; rt < 2; rt++)
#pragma unroll
        for (int i = 0; i < 4; i++) {
            const int rl = rowbase + 16 * rt + quad * 4 + i;
            const int n = (row0 + rl) & (S_ - 1);
            float keep = 1.f;
            if (EPI == 1) keep = (n == 0) ? 1.f : (mask[b * N_ + n - 1] ? 0.f : 1.f);
#pragma unroll
            for (int ct = 0; ct < 4; ct++) {
                float c = acc[rt][ct][i] + bv[ct];
                if (EPI == 1) c *= keep;
                const int col = colv[ct];
                out[(((size_t)b * H_ + (col >> 5)) * S_ + n) * DH_ + (col & 31)] = c;
            }
        }
    } else if (EPI == 2) {
        float gv[4], bbv[4];
#pragma unroll
        for (int ct = 0; ct < 4; ct++) { gv[ct] = g1[colv[ct]]; bbv[ct] = g2[colv[ct]]; }
#pragma unroll
        for (int rt = 0; rt < 2; rt++)
#pragma unroll
        for (int i = 0; i < 4; i++) {
            const int rl = rowbase + 16 * rt + quad * 4 + i;
            float s = 0.f, s2 = 0.f;
#pragma unroll
            for (int ct = 0; ct < 4; ct++) {
                const float c = acc[rt][ct][i] + bv[ct];
                s += c; s2 += c * c;
            }
#pragma unroll
            for (int o = 8; o > 0; o >>= 1) { s += __shfl_xor(s, o, 64); s2 += __shfl_xor(s2, o, 64); }
            if (l16 == 0) { sredA[rl][colg] = s; sredB[rl][colg] = s2; }
        }
        __syncthreads();
#pragma unroll
        for (int rt = 0; rt < 2; rt++)
#pragma unroll
        for (int i = 0; i < 4; i++) {
            const int rl = rowbase + 16 * rt + quad * 4 + i;
            const float s = sredA[rl][0] + sredA[rl][1] + sredA[rl][2] + sredA[rl][3];
            const float s2 = sredB[rl][0] + sredB[rl][1] + sredB[rl][2] + sredB[rl][3];
            const float mu = s * (1.f / D_);
            const float rs = rsqrtf(s2 * (1.f / D_) - mu * mu + 1e-5f);
#pragma unroll
            for (int ct = 0; ct < 4; ct++) {
                const float c = acc[rt][ct][i] + bv[ct];
                out[(size_t)(row0 + rl) * D_ + colv[ct]] = (c - mu) * rs * gv[ct] + bbv[ct];
            }
        }
    } else {
#pragma unroll
        for (int rt = 0; rt < 2; rt++)
#pragma unroll
        for (int i = 0; i < 4; i++) {
            const int rl = rowbase + 16 * rt + quad * 4 + i;
#pragma unroll
            for (int ct = 0; ct < 4; ct++) {
                const float c = acc[rt][ct][i] + bv[ct];
                out[(size_t)(row0 + rl) * D_ + colv[ct]] = (c >= 0.f) ? c : 0.2f * c;
            }
        }
    }
}

// ---------- reset kmax slots ----------
__global__ void k_reset(int* slots) {
    if (threadIdx.x < 4) {
        const int i = __float_as_int(-INFINITY);
        slots[threadIdx.x] = (i >= 0) ? i : (i ^ 0x7fffffff);
    }
}

// ---------- MFMA global k-max (proven) ----------
__global__ void __launch_bounds__(256) k_dmax(
    const float* __restrict__ kg, const unsigned* __restrict__ P2, int* __restrict__ slot)
{
    __shared__ __align__(16) ushort A2s[64 * 136];
    __shared__ __align__(16) ushort Ps[128 * 136];
    __shared__ float sred[4];
    const int t = threadIdx.x;
    const size_t row0 = (size_t)(blockIdx.x >> 1) * 64;
    const int m0 = (blockIdx.x & 1) * 128;
    {
        const int row = t >> 2, kq = (t & 3) * 8;
        const float* src = kg + (row0 + row) * DH_ + kq;
        const float4 f0 = *(const float4*)src;
        const float4 f1 = *(const float4*)(src + 4);
        const float vv[8] = {f0.x, f0.y, f0.z, f0.w, f1.x, f1.y, f1.z, f1.w};
#pragma unroll
        for (int i = 0; i < 4; i++) {
            unsigned hh0, ll0, hh1, ll1;
            split2(vv[2 * i], hh0, ll0); split2(vv[2 * i + 1], hh1, ll1);
            *(uint4*)&A2s[row * 136 + ((t & 3) * 4 + i) * 8] = make_uint4(hh0, ll0, hh1, ll1);
        }
    }
    {
        const int col = t >> 1;
        const unsigned* src = P2 + (m0 + col) * DH_ + (t & 1) * 16;
#pragma unroll
        for (int i = 0; i < 8; i++) {
            const unsigned u0 = src[2 * i], u1 = src[2 * i + 1];
            *(uint4*)&Ps[col * 136 + ((t & 1) * 8 + i) * 8] = make_uint4(u0, u0, u1, u1);
        }
    }
    __syncthreads();
    const int w = t >> 6, lane = t & 63, quad = lane >> 4, l16 = lane & 15;
    floatx4 acc[4][2];
#pragma unroll
    for (int rt = 0; rt < 4; rt++)
#pragma unroll
        for (int ct = 0; ct < 2; ct++) acc[rt][ct] = (floatx4){0.f, 0.f, 0.f, 0.f};
#pragma unroll
    for (int kk = 0; kk < 4; kk++) {
        short8 af[4], bf[2];
#pragma unroll
        for (int rt = 0; rt < 4; rt++)
            af[rt] = *(const short8*)&A2s[(rt * 16 + l16) * 136 + (kk * 4 + quad) * 8];
#pragma unroll
        for (int ct = 0; ct < 2; ct++)
            bf[ct] = *(const short8*)&Ps[((w * 2 + ct) * 16 + l16) * 136 + (kk * 4 + quad) * 8];
#pragma unroll
        for (int rt = 0; rt < 4; rt++)
#pragma unroll
            for (int ct = 0; ct < 2; ct++)
                acc[rt][ct] = __builtin_amdgcn_mfma_f32_16x16x32_bf16(af[rt], bf[ct], acc[rt][ct], 0, 0, 0);
    }
    float mx = -INFINITY;
#pragma unroll
    for (int rt = 0; rt < 4; rt++)
#pragma unroll
        for (int ct = 0; ct < 2; ct++)
#pragma unroll
            for (int i = 0; i < 4; i++) mx = fmaxf(mx, acc[rt][ct][i]);
#pragma unroll
    for (int o = 32; o > 0; o >>= 1) mx = fmaxf(mx, __shfl_xor(mx, o, 64));
    if (lane == 0) sred[w] = mx;
    __syncthreads();
    if (t == 0) {
        const float m4 = fmaxf(fmaxf(sred[0], sred[1]), fmaxf(sred[2], sred[3]))
                       * 0.42044820762685725f;
        const int i = __float_as_int(m4);
        atomicMax(slot, (i >= 0) ? i : (i ^ 0x7fffffff));
    }
}

// ---------- full-MFMA performer attention, 1024 threads (16 waves), 140 KB LDS ----------
__global__ void __launch_bounds__(1024) k_attn2(
    const float* __restrict__ qg, const float* __restrict__ kg, const float* __restrict__ vg,
    const unsigned* __restrict__ P2, const int* __restrict__ slot,
    float* __restrict__ outp)
{
    extern __shared__ char smem[];
    ushort* sA    = (ushort*)(smem);            // [128][136]: K-split, then Q-split
    ushort* sB    = (ushort*)(smem + 34816);    // [64][136]: P-quarter {h,l,h,l}
    ushort* sBig  = (ushort*)(smem + 52224);    // kpT [64][264] / qpA [128][136]
    ushort* sV    = (ushort*)(smem + 87040);    // [32][264]: v dup
    ushort* sCtx  = (ushort*)(smem + 103936);   // [32][520]: ctx dup
    float* sdk    = (float*)(smem + 137216);    // [128]
    float* sdq    = (float*)(smem + 137728);    // [128]
    float* smaxP  = (float*)(smem + 138240);    // [2][128]
    float* sdenP  = (float*)(smem + 139264);    // [2][128]
    float* sksum  = (float*)(smem + 140288);    // [256]
    float* sksP   = (float*)(smem + 141312);    // [16][32]

    const int bh = blockIdx.x;
    const int b = bh >> 3, hh = bh & 7;
    const int t = threadIdx.x;
    const int w = t >> 6, lane = t & 63, quad = lane >> 4, l16 = lane & 15;
    const int wg = w & 7, wh = w >> 3;
    const float* kb = kg + (size_t)bh * S_ * DH_;
    const float* qb = qg + (size_t)bh * S_ * DH_;
    const float* vb = vg + (size_t)bh * S_ * DH_;
    const float nrm = 0.42044820762685725f;
    const float diagc = 0.5f * nrm * nrm;
    const float ratio = 0.0625f;

    if (t < 512) {
        const int row = t >> 2, seg = t & 3;
        const float* src = kb + row * DH_ + seg * 8;
        float vv[8];
        *(float4*)&vv[0] = *(const float4*)&src[0];
        *(float4*)&vv[4] = *(const float4*)&src[4];
#pragma unroll
        for (int p = 0; p < 4; p++) {
            unsigned hh0, ll0, hh1, ll1;
            split2(vv[2 * p], hh0, ll0); split2(vv[2 * p + 1], hh1, ll1);
            *(uint4*)&sA[row * 136 + seg * 32 + p * 8] = make_uint4(hh0, ll0, hh1, ll1);
        }
    } else {
        const int tt2 = t - 512;
        const int n = tt2 & 127, d0 = (tt2 >> 7) * 8;
        const float* src = vb + n * DH_ + d0;
        float vv[8];
        *(float4*)&vv[0] = *(const float4*)&src[0];
        *(float4*)&vv[4] = *(const float4*)&src[4];
        unsigned* dst = (unsigned*)sV;
#pragma unroll
        for (int j = 0; j < 8; j++)
            dst[(d0 + j) * 132 + n] = (unsigned)bf16_rn(vv[j]) * 0x10001u;
    }
    if (t < 128) {
        float s = 0.f, s2 = 0.f;
#pragma unroll
        for (int d4 = 0; d4 < DH_ / 4; d4++) {
            const float4 kk = *(const float4*)&kb[t * DH_ + d4 * 4];
            s += kk.x * kk.x + kk.y * kk.y + kk.z * kk.z + kk.w * kk.w;
            const float4 qq = *(const float4*)&qb[t * DH_ + d4 * 4];
            s2 += qq.x * qq.x + qq.y * qq.y + qq.z * qq.z + qq.w * qq.w;
        }
        sdk[t] = s * diagc;
        sdq[t] = s2 * diagc;
    }
    float kmaxv;
    { const int iv = *slot; kmaxv = __int_as_float((iv >= 0) ? iv : (iv ^ 0x7fffffff)); }
    __syncthreads();

    for (int qd = 0; qd < 4; qd++) {
        {
            const int col = t >> 4, ch2 = t & 15;
            const unsigned* src = P2 + (size_t)(qd * 64 + col) * DH_ + ch2 * 2;
            const unsigned u0 = src[0], u1 = src[1];
            *(uint4*)&sB[col * 136 + ch2 * 8] = make_uint4(u0, u0, u1, u1);
        }
        __syncthreads();
        floatx4 acc[2];
        acc[0] = (floatx4){0.f, 0.f, 0.f, 0.f};
        acc[1] = (floatx4){0.f, 0.f, 0.f, 0.f};
#pragma unroll
        for (int ks = 0; ks < 4; ks++) {
            const short8 af = *(const short8*)&sA[(wg * 16 + l16) * 136 + ks * 32 + quad * 8];
            short8 bf[2];
#pragma unroll
            for (int ctl = 0; ctl < 2; ctl++)
                bf[ctl] = *(const short8*)&sB[((2 * wh + ctl) * 16 + l16) * 136 + ks * 32 + quad * 8];
#pragma unroll
            for (int ctl = 0; ctl < 2; ctl++)
                acc[ctl] = __builtin_amdgcn_mfma_f32_16x16x32_bf16(af, bf[ctl], acc[ctl], 0, 0, 0);
        }
        unsigned* kpT = (unsigned*)sBig;
        float kc[2];
#pragma unroll
        for (int ctl = 0; ctl < 2; ctl++) {
            float kcl = 0.f;
            unsigned pk[4];
#pragma unroll
            for (int i = 0; i < 4; i++) {
                const int n = wg * 16 + quad * 4 + i;
                const float kp = ratio * (exp2f((acc[ctl][i] * nrm - sdk[n] - kmaxv) * LOG2E) + 1e-4f);
                kcl += kp;
                pk[i] = split_pack(kp);
            }
            *(uint4*)&kpT[((2 * wh + ctl) * 16 + l16) * 132 + wg * 16 + quad * 4] =
                make_uint4(pk[0], pk[1], pk[2], pk[3]);
            kc[ctl] = kcl;
        }
#pragma unroll
        for (int ctl = 0; ctl < 2; ctl++) {
            kc[ctl] += __shfl_xor(kc[ctl], 16, 64);
            kc[ctl] += __shfl_xor(kc[ctl], 32, 64);
        }
        if (quad == 0) {
            sksP[w * 32 + l16] = kc[0];
            sksP[w * 32 + 16 + l16] = kc[1];
        }
        __syncthreads();
        if (t < 64) {
            float s = 0.f;
#pragma unroll
            for (int wg2 = 0; wg2 < 8; wg2++)
                s += sksP[((t >> 5) * 8 + wg2) * 32 + (t & 31)];
            sksum[qd * 64 + t] = s;
        }
        if (w < 8) {
            const int mt = w & 3, dt = w >> 2;
            floatx4 cacc = (floatx4){0.f, 0.f, 0.f, 0.f};
#pragma unroll
            for (int ks = 0; ks < 8; ks++) {
                const short8 a = *(const short8*)&sBig[(mt * 16 + l16) * 264 + ks * 32 + quad * 8];
                const short8 bvv = *(const short8*)&sV[(dt * 16 + l16) * 264 + ks * 32 + quad * 8];
                cacc = __builtin_amdgcn_mfma_f32_16x16x32_bf16(a, bvv, cacc, 0, 0, 0);
            }
            unsigned* ctxB = (unsigned*)sCtx;
            unsigned pk[4];
#pragma unroll
            for (int i = 0; i < 4; i++) pk[i] = (unsigned)bf16_rn(cacc[i]) * 0x10001u;
            *(uint4*)&ctxB[(dt * 16 + l16) * 260 + qd * 64 + mt * 16 + quad * 4] =
                make_uint4(pk[0], pk[1], pk[2], pk[3]);
        }
        __syncthreads();
    }

    if (t < 512) {
        const int row = t >> 2, seg = t & 3;
        const float* src = qb + row * DH_ + seg * 8;
        float vv[8];
        *(float4*)&vv[0] = *(const float4*)&src[0];
        *(float4*)&vv[4] = *(const float4*)&src[4];
#pragma unroll
        for (int p = 0; p < 4; p++) {
            unsigned hh0, ll0, hh1, ll1;
            split2(vv[2 * p], hh0, ll0); split2(vv[2 * p + 1], hh1, ll1);
            *(uint4*)&sA[row * 136 + seg * 32 + p * 8] = make_uint4(hh0, ll0, hh1, ll1);
        }
    }

    floatx4 adq[4][2];
#pragma unroll
    for (int qd = 0; qd < 4; qd++) {
        {
            const int col = t >> 4, ch2 = t & 15;
            const unsigned* src = P2 + (size_t)(qd * 64 + col) * DH_ + ch2 * 2;
            const unsigned u0 = src[0], u1 = src[1];
            *(uint4*)&sB[col * 136 + ch2 * 8] = make_uint4(u0, u0, u1, u1);
        }
        __syncthreads();
        adq[qd][0] = (floatx4){0.f, 0.f, 0.f, 0.f};
        adq[qd][1] = (floatx4){0.f, 0.f, 0.f, 0.f};
#pragma unroll
        for (int ks = 0; ks < 4; ks++) {
            const short8 bf = *(const short8*)&sA[(wg * 16 + l16) * 136 + ks * 32 + quad * 8];
            short8 af[2];
#pragma unroll
            for (int mtl = 0; mtl < 2; mtl++)
                af[mtl] = *(const short8*)&sB[((2 * wh + mtl) * 16 + l16) * 136 + ks * 32 + quad * 8];
#pragma unroll
            for (int mtl = 0; mtl < 2; mtl++)
                adq[qd][mtl] = __builtin_amdgcn_mfma_f32_16x16x32_bf16(af[mtl], bf, adq[qd][mtl], 0, 0, 0);
        }
        __syncthreads();
    }

    const int nq = wg * 16 + l16;
    {
        float mxn = -INFINITY;
#pragma unroll
        for (int qd = 0; qd < 4; qd++)
#pragma unroll
            for (int mtl = 0; mtl < 2; mtl++)
#pragma unroll
                for (int i = 0; i < 4; i++) mxn = fmaxf(mxn, adq[qd][mtl][i]);
        mxn = fmaxf(mxn, __shfl_xor(mxn, 16, 64));
        mxn = fmaxf(mxn, __shfl_xor(mxn, 32, 64));
        if (quad == 0) smaxP[wh * 128 + nq] = mxn;
    }
    __syncthreads();
    const float dmq = sdq[nq] + fmaxf(smaxP[nq], smaxP[128 + nq]) * nrm;

    floatx4 oacc = (floatx4){0.f, 0.f, 0.f, 0.f};
    float dp = 0.f;
#pragma unroll
    for (int qd = 0; qd < 4; qd++) {
        unsigned* qpA = (unsigned*)sBig;
#pragma unroll
        for (int mtl = 0; mtl < 2; mtl++) {
            unsigned pk[4];
#pragma unroll
            for (int i = 0; i < 4; i++) {
                const float qp = ratio * (exp2f((adq[qd][mtl][i] * nrm - dmq) * LOG2E) + 1e-4f);
                dp += qp * sksum[qd * 64 + (2 * wh + mtl) * 16 + quad * 4 + i];
                pk[i] = split_pack(qp);
            }
            *(uint4*)&qpA[nq * 68 + (2 * wh + mtl) * 16 + quad * 4] = make_uint4(pk[0], pk[1], pk[2], pk[3]);
        }
        __syncthreads();
#pragma unroll
        for (int ks = 0; ks < 4; ks++) {
            const short8 af = *(const short8*)&sBig[(wg * 16 + l16) * 136 + ks * 32 + quad * 8];
            const short8 bf = *(const short8*)&sCtx[(wh * 16 + l16) * 520 + qd * 128 + ks * 32 + quad * 8];
            oacc = __builtin_amdgcn_mfma_f32_16x16x32_bf16(af, bf, oacc, 0, 0, 0);
        }
        __syncthreads();
    }
    dp += __shfl_xor(dp, 16, 64);
    dp += __shfl_xor(dp, 32, 64);
    if (quad == 0) sdenP[wh * 128 + nq] = dp;
    __syncthreads();

#pragma unroll
    for (int i = 0; i < 4; i++) {
        const int n = wg * 16 + quad * 4 + i;
        const float inv = 1.0f / (sdenP[n] + sdenP[128 + n]);
        outp[((size_t)b * S_ + n) * D_ + hh * DH_ + wh * 16 + l16] = oacc[i] * inv;
    }
}

// ---------- classification head ----------
__global__ void __launch_bounds__(256) k_head(
    const float* __restrict__ hfin, const float* __restrict__ h1w, const float* __restrict__ h1b,
    const float* __restrict__ h2w, const float* __restrict__ h2b,
    const float* __restrict__ ow, const float* __restrict__ ob, float* __restrict__ outp)
{
    __shared__ float c0[D_];
    __shared__ float c1[2 * HID_];
    __shared__ float sred[4];
    const int t = threadIdx.x;
    const int b = blockIdx.x;
    c0[t] = hfin[(size_t)b * S_ * D_ + t];
    __syncthreads();
#pragma unroll
    for (int half = 0; half < 2; half++) {
        const int j = half * 256 + t;
        float a = h1b[j];
        const float* w = h1w + (size_t)j * D_;
        for (int d = 0; d < D_; d += 4) {
            const float4 w4 = *(const float4*)&w[d];
            const float4 x4 = *(const float4*)&c0[d];
            a += x4.x * w4.x + x4.y * w4.y + x4.z * w4.z + x4.w * w4.w;
        }
        c1[j] = (a >= 0.f) ? a : 0.2f * a;
    }
    __syncthreads();
    float a2 = h2b[t];
    const float* w2 = h2w + (size_t)t * (2 * HID_);
    for (int j = 0; j < 2 * HID_; j += 4) {
        const float4 w4 = *(const float4*)&w2[j];
        const float4 x4 = *(const float4*)&c1[j];
        a2 += x4.x * w4.x + x4.y * w4.y + x4.z * w4.z + x4.w * w4.w;
    }
    const float c2 = (a2 >= 0.f) ? a2 : 0.2f * a2;
    const float s = blk_sum(c2 * ow[t], sred);
    if (t == 0) outp[b] = s + ob[0];
}

extern "C" void kernel_launch(void* const* d_in, const int* in_sizes, int n_in,
                              void* d_out, int out_size, void* d_ws, size_t ws_size,
                              hipStream_t stream)
{
    const float* x     = (const float*)d_in[0];
    const int*   mask  = (const int*)d_in[1];
    const float* emb_w = (const float*)d_in[2];
    const float* emb_b = (const float*)d_in[3];
    const float* Wq    = (const float*)d_in[4];
    const float* bq    = (const float*)d_in[5];
    const float* Wk    = (const float*)d_in[6];
    const float* bk    = (const float*)d_in[7];
    const float* Wv    = (const float*)d_in[8];
    const float* bv    = (const float*)d_in[9];
    const float* Wo    = (const float*)d_in[10];
    const float* bo    = (const float*)d_in[11];
    const float* proj  = (const float*)d_in[12];
    const float* n1w   = (const float*)d_in[13];
    const float* n1b   = (const float*)d_in[14];
    const float* n2w   = (const float*)d_in[15];
    const float* n2b   = (const float*)d_in[16];
    const float* f1w   = (const float*)d_in[17];
    const float* f1b   = (const float*)d_in[18];
    const float* f2w   = (const float*)d_in[19];
    const float* f2b   = (const float*)d_in[20];
    const float* h1w   = (const float*)d_in[21];
    const float* h1b   = (const float*)d_in[22];
    const float* h2w   = (const float*)d_in[23];
    const float* h2b   = (const float*)d_in[24];
    const float* ow    = (const float*)d_in[25];
    const float* ob    = (const float*)d_in[26];

    const size_t BSD = (size_t)B_ * S_ * D_;
    float* A = (float*)d_ws;
    float* Q = A + BSD;
    float* K = Q + BSD;
    float* V = K + BSD;
    float* T = K;                              // post-LN1 alias (K dead after attn)
    unsigned* W2 = (unsigned*)(V + BSD);       // compact split weights: 6 x L x 65536 uints
    const size_t WT = (size_t)L_ * 256 * 256;
    const size_t WM = (size_t)256 * 256;
    unsigned* P2 = W2 + 6 * WT;                // compact split proj: L x 256 x 32 uints
    int* slots = (int*)(P2 + (size_t)L_ * M_ * DH_);

    k_wconv<<<256, 256, 0, stream>>>(Wq,  W2 + 0 * WT);
    k_wconv<<<256, 256, 0, stream>>>(Wk,  W2 + 1 * WT);
    k_wconv<<<256, 256, 0, stream>>>(Wv,  W2 + 2 * WT);
    k_wconv<<<256, 256, 0, stream>>>(Wo,  W2 + 3 * WT);
    k_wconv<<<256, 256, 0, stream>>>(f1w, W2 + 4 * WT);
    k_wconv<<<256, 256, 0, stream>>>(f2w, W2 + 5 * WT);
    k_wconv<<<32, 256, 0, stream>>>(proj, P2);
    k_reset<<<1, 64, 0, stream>>>(slots);

    const int GB = B_ * S_ / 64;               // 512 blocks per GEMM
    const int DB = B_ * H_ * S_ / 64 * 2;      // 8192 blocks for k_dmax
    const size_t ATTN_LDS = 143360;            // 140 KB dynamic LDS

    k_embed<<<B_ * S_ * D_ / 256, 256, 0, stream>>>(x, emb_w, emb_b, A);
    for (int l = 0; l < L_; l++) {
        const unsigned* P2l = P2 + (size_t)l * M_ * DH_;
        k_gemm<0><<<GB, 512, 0, stream>>>(A, W2 + 0 * WT + l * WM, bq + l * D_, nullptr, nullptr, nullptr, Q);
        k_gemm<0><<<GB, 512, 0, stream>>>(A, W2 + 1 * WT + l * WM, bk + l * D_, nullptr, nullptr, nullptr, K);
        k_gemm<1><<<GB, 512, 0, stream>>>(A, W2 + 2 * WT + l * WM, bv + l * D_, nullptr, nullptr, mask, V);
        k_dmax<<<DB, 256, 0, stream>>>(K, P2l, slots + l);
        k_attn2<<<B_ * H_, 1024, ATTN_LDS, stream>>>(Q, K, V, P2l, slots + l, A);
        k_gemm<2><<<GB, 512, 0, stream>>>(A, W2 + 3 * WT + l * WM, bo + l * D_, n1w + l * D_, n1b + l * D_, nullptr, T);
        k_gemm<3><<<GB, 512, 0, stream>>>(T, W2 + 4 * WT + l * WM, f1b + l * HID_, nullptr, nullptr, nullptr, Q);
        k_gemm<2><<<GB, 512, 0, stream>>>(Q, W2 + 5 * WT + l * WM, f2b + l * D_, n2w + l * D_, n2b + l * D_, nullptr, A);
    }
    k_head<<<B_, 256, 0, stream>>>(A, h1w, h1b, h2w, h2b, ow, ob, (float*)d_out);
}